// Round 1
// baseline (4000.304 us; speedup 1.0000x reference)
//
#include <hip/hip_runtime.h>
#include <hip/hip_bf16.h>

// ---------------------------------------------------------------------------
// PointerGenerator forward, MI355X.
// Key identity: softmax_l(enc_att + const_b) == softmax_l(enc_att)  =>
// attention weights / context / copy-dist are decoder-step-invariant.
// Decoder reduces to an LSTM scan + one big parallel vocab GEMM.
//
// R1: k_scan was at ~85% of the per-CU L2 BW roofline (512KB Whh re-streamed
// from L2 every step, 47.7 B/cyc/CU vs ~56-60 ceiling). Rebuilt as a
// weight-stationary scan: 1024 thr/block, Whh column resident in 92 VGPRs +
// 147KB LDS per block; zero weight traffic from L2 in the steady loop.
// ---------------------------------------------------------------------------

#define DEVINL __device__ __forceinline__

typedef _Float16 f16;
typedef _Float16 f16x2 __attribute__((ext_vector_type(2)));
typedef _Float16 f16x8 __attribute__((ext_vector_type(8)));
typedef short    s16x8 __attribute__((ext_vector_type(8)));
typedef float    f32x4 __attribute__((ext_vector_type(4)));

DEVINL float dot2f(unsigned int a, unsigned int b, float acc) {
#if __has_builtin(__builtin_amdgcn_fdot2)
  return __builtin_amdgcn_fdot2(__builtin_bit_cast(f16x2, a),
                                __builtin_bit_cast(f16x2, b), acc, false);
#else
  f16x2 x = __builtin_bit_cast(f16x2, a);
  f16x2 y = __builtin_bit_cast(f16x2, b);
  return acc + (float)x[0] * (float)y[0] + (float)x[1] * (float)y[1];
#endif
}

DEVINL float sigm(float x) { return 1.0f / (1.0f + __expf(-x)); }
DEVINL float tanh_f(float x) {
  float e = __expf(2.0f * x);
  return (e - 1.0f) / (e + 1.0f);
}
DEVINL unsigned int pack2(float a, float b) {
  f16x2 p; p[0] = (f16)a; p[1] = (f16)b;
  return __builtin_bit_cast(unsigned int, p);
}

// ---------------------------------------------------------------------------
// Weight packing
// ---------------------------------------------------------------------------

// Whh (1024 x 256 fp32) -> Wp[k2b][j] uint4, k2b in [0,32) covers k=8*k2b..+7
__global__ __launch_bounds__(256) void k_pack_whh(const float* __restrict__ W,
                                                  uint4* __restrict__ dst) {
  int id = blockIdx.x * 256 + threadIdx.x;       // 32768
  int k2b = id >> 10, j = id & 1023;
  const float* s = W + (size_t)j * 256 + k2b * 8;
  uint4 u;
  u.x = pack2(s[0], s[1]); u.y = pack2(s[2], s[3]);
  u.z = pack2(s[4], s[5]); u.w = pack2(s[6], s[7]);
  dst[k2b * 1024 + j] = u;
}

// Wih (1024 x ldk fp32, first 128 cols) -> W2[j][k2] uint (half2), k2<64
__global__ __launch_bounds__(256) void k_pack_wih(const float* __restrict__ W,
                                                  unsigned int* __restrict__ dst,
                                                  int ldk) {
  int id = blockIdx.x * 256 + threadIdx.x;       // 65536
  int j = id >> 6, k2 = id & 63;
  dst[j * 64 + k2] = pack2(W[(size_t)j * ldk + 2 * k2],
                           W[(size_t)j * ldk + 2 * k2 + 1]);
}

__global__ __launch_bounds__(256) void k_pack_vpw(const float* __restrict__ W,
                                                  __hip_bfloat16* __restrict__ dst) {
  size_t id = (size_t)blockIdx.x * 256 + threadIdx.x;   // 24,576,000
  dst[id] = __float2bfloat16(W[id]);
}

// ---------------------------------------------------------------------------
// Encoder input projection: X[row][b][j] = emb[b][l] @ Wih.T + bias, f16 out.
// One block per l (256 thr). rev=1 stores to row 511-l (backward direction).
// ---------------------------------------------------------------------------
__global__ __launch_bounds__(256) void k_encproj(
    const int* __restrict__ source, const float* __restrict__ emb,
    const unsigned int* __restrict__ W2, const float* __restrict__ bias,
    f16* __restrict__ X, int rev) {
  int l = blockIdx.x;
  int tid = threadIdx.x;
  __shared__ int toks[32];
  __shared__ unsigned int e2[32 * 66];    // padded rows: bank spread
  if (tid < 32) toks[tid] = source[tid * 512 + l];
  __syncthreads();
  {
    int row = tid >> 3;
    int k2b = (tid & 7) * 8;
    const float* er = emb + (size_t)toks[row] * 128 + k2b * 2;
#pragma unroll
    for (int i = 0; i < 8; ++i)
      e2[row * 66 + k2b + i] = pack2(er[2 * i], er[2 * i + 1]);
  }
  __syncthreads();
  int jg = tid >> 3;        // 0..31 -> j-octet
  int bq = (tid & 7) * 4;   // batch quad base
  int orow = rev ? (511 - l) : l;
  for (int jt = 0; jt < 4; ++jt) {
    int j0 = jt * 256 + jg * 8;
    float acc[8][4];
#pragma unroll
    for (int jj = 0; jj < 8; ++jj) {
      float bv = bias[j0 + jj];
#pragma unroll
      for (int bb = 0; bb < 4; ++bb) acc[jj][bb] = bv;
    }
    for (int kp = 0; kp < 32; ++kp) {
      uint2 w[8], e[4];
#pragma unroll
      for (int jj = 0; jj < 8; ++jj)
        w[jj] = *(const uint2*)(W2 + (size_t)(j0 + jj) * 64 + kp * 2);
#pragma unroll
      for (int bb = 0; bb < 4; ++bb)
        e[bb] = *(const uint2*)(e2 + (bq + bb) * 66 + kp * 2);
#pragma unroll
      for (int jj = 0; jj < 8; ++jj)
#pragma unroll
        for (int bb = 0; bb < 4; ++bb) {
          acc[jj][bb] = dot2f(e[bb].x, w[jj].x, acc[jj][bb]);
          acc[jj][bb] = dot2f(e[bb].y, w[jj].y, acc[jj][bb]);
        }
    }
#pragma unroll
    for (int bb = 0; bb < 4; ++bb) {
      f16x8 v;
#pragma unroll
      for (int jj = 0; jj < 8; ++jj) v[jj] = (f16)acc[jj][bb];
      *(f16x8*)(X + ((size_t)orow * 32 + bq + bb) * 1024 + j0) = v;
    }
  }
}

// ---------------------------------------------------------------------------
// Decoder input projection (emb part only; context part comes via cprj which
// already includes dec_b). Also emits pemb[t][b] = emb_t . pg_W[768:896].
// ---------------------------------------------------------------------------
__global__ __launch_bounds__(256) void k_decproj(
    const int* __restrict__ target, const float* __restrict__ emb,
    const unsigned int* __restrict__ W2, const float* __restrict__ cprj,
    const float* __restrict__ pgW, f16* __restrict__ X,
    float* __restrict__ pemb) {
  int t = blockIdx.x;
  int tid = threadIdx.x;
  __shared__ int toks[32];
  __shared__ unsigned int e2[32 * 66];
  if (tid < 32) toks[tid] = (t == 0) ? 0 : target[tid * 64 + t - 1];
  __syncthreads();
  {
    int row = tid >> 3;
    int k2b = (tid & 7) * 8;
    const float* er = emb + (size_t)toks[row] * 128 + k2b * 2;
#pragma unroll
    for (int i = 0; i < 8; ++i)
      e2[row * 66 + k2b + i] = pack2(er[2 * i], er[2 * i + 1]);
  }
  __syncthreads();
  if (tid < 32) {
    float s = 0.f;
    for (int k2 = 0; k2 < 64; ++k2) {
      f16x2 p = __builtin_bit_cast(f16x2, e2[tid * 66 + k2]);
      s += (float)p[0] * pgW[768 + 2 * k2] + (float)p[1] * pgW[768 + 2 * k2 + 1];
    }
    pemb[t * 32 + tid] = s;
  }
  int jg = tid >> 3;
  int bq = (tid & 7) * 4;
  for (int jt = 0; jt < 4; ++jt) {
    int j0 = jt * 256 + jg * 8;
    float acc[8][4];
#pragma unroll
    for (int jj = 0; jj < 8; ++jj)
#pragma unroll
      for (int bb = 0; bb < 4; ++bb)
        acc[jj][bb] = cprj[(size_t)(bq + bb) * 1024 + j0 + jj];
    for (int kp = 0; kp < 32; ++kp) {
      uint2 w[8], e[4];
#pragma unroll
      for (int jj = 0; jj < 8; ++jj)
        w[jj] = *(const uint2*)(W2 + (size_t)(j0 + jj) * 64 + kp * 2);
#pragma unroll
      for (int bb = 0; bb < 4; ++bb)
        e[bb] = *(const uint2*)(e2 + (bq + bb) * 66 + kp * 2);
#pragma unroll
      for (int jj = 0; jj < 8; ++jj)
#pragma unroll
        for (int bb = 0; bb < 4; ++bb) {
          acc[jj][bb] = dot2f(e[bb].x, w[jj].x, acc[jj][bb]);
          acc[jj][bb] = dot2f(e[bb].y, w[jj].y, acc[jj][bb]);
        }
    }
#pragma unroll
    for (int bb = 0; bb < 4; ++bb) {
      f16x8 v;
#pragma unroll
      for (int jj = 0; jj < 8; ++jj) v[jj] = (f16)acc[jj][bb];
      *(f16x8*)(X + ((size_t)t * 32 + bq + bb) * 1024 + j0) = v;
    }
  }
}

// ---------------------------------------------------------------------------
// LSTM scan v2 — weight-stationary. 1024 threads, 2 batches per block,
// thread tid owns gate column j=tid for both batches.
// Whh column (128 packed f16x2 words = 32 uint4 quads) is resident:
//   quads [0,23)  -> 92 VGPRs per thread (persist across all steps)
//   quads [23,32) -> 147456B of LDS (filled once, full-rate b128 reads)
// Steady-state loop streams ZERO weight bytes from L2 (was 512KB/CU/step,
// which was ~85% of the ~56 B/cyc/CU L2 ceiling = the old bottleneck).
// mode 0: encoder (grid 32, dir=bid>>4), mode 2: decoder (grid 16).
// Dynamic LDS: 147456 (W) + 1024 (hh) + 8192 (gates) = 156672 B.
// ---------------------------------------------------------------------------
#define QDOT(h0v, h1v, wv)                                                  \
  a0 = dot2f((h0v).x, (wv).x, a0); a1 = dot2f((h1v).x, (wv).x, a1);         \
  a0 = dot2f((h0v).y, (wv).y, a0); a1 = dot2f((h1v).y, (wv).y, a1);         \
  a0 = dot2f((h0v).z, (wv).z, a0); a1 = dot2f((h1v).z, (wv).z, a1);         \
  a0 = dot2f((h0v).w, (wv).w, a0); a1 = dot2f((h1v).w, (wv).w, a1);

__global__ __launch_bounds__(1024, 4) void k_scan(
    const uint4* __restrict__ Wp0, const f16* __restrict__ X0,
    float* __restrict__ out, float* __restrict__ cf,
    const float* __restrict__ hinit, int mode, int nsteps) {
  extern __shared__ char smem[];
  uint4* WL    = (uint4*)smem;                 // [9][1024] uint4
  f16*   hh    = (f16*)(smem + 147456);        // [2][256]
  float* gates = (float*)(smem + 148480);      // [2][1024]
  int bid = blockIdx.x;
  int dir  = (mode == 2) ? 0 : (bid >> 4);
  int pair = (mode == 2) ? bid : (bid & 15);
  int isbw = (mode != 2) && (dir == 1);
  int isdec = (mode == 2);
  const uint4* Wp = Wp0 + (size_t)dir * 32768;
  const f16* X = X0 + (size_t)dir * 16777216;
  int tid = threadIdx.x;
  int j = tid;                    // gate column 0..1023
  int b0 = pair * 2;
  int bl = tid >> 8, jh = tid & 255;   // activation role (tid<512 only)
  int bg = b0 + bl;

  // --- load resident weights (once) ---
  uint4 wr[23];
#pragma unroll
  for (int q = 0; q < 23; ++q) wr[q] = Wp[(q << 10) | j];
#pragma unroll
  for (int q = 0; q < 9; ++q) WL[q * 1024 + j] = Wp[((q + 23) << 10) | j];

  float c_reg = 0.f;
  if (tid < 512) {
    if (isdec) {
      c_reg = cf[bg * 256 + jh];
      hh[bl * 256 + jh] = (f16)hinit[((size_t)bg * 512 + 511) * 512 + jh];
    } else {
      hh[bl * 256 + jh] = (f16)0.f;
    }
  }
  __syncthreads();
  const uint4* h0p = (const uint4*)hh;
  const uint4* h1p = (const uint4*)(hh + 256);

  for (int t = 0; t < nsteps; ++t) {
    const f16* x0 = X + ((size_t)t * 32 + b0) * 1024;
    float a0 = (float)x0[j];
    float a1 = (float)x0[1024 + j];
#pragma unroll
    for (int q = 0; q < 23; ++q) {
      uint4 h0 = h0p[q], h1 = h1p[q];
      QDOT(h0, h1, wr[q]);
    }
#pragma unroll
    for (int q = 0; q < 9; ++q) {
      uint4 w = WL[q * 1024 + j];
      uint4 h0 = h0p[23 + q], h1 = h1p[23 + q];
      QDOT(h0, h1, w);
    }
    gates[j] = a0;
    gates[1024 + j] = a1;
    __syncthreads();
    if (tid < 512) {
      float gi  = gates[bl * 1024 + jh];
      float gf_ = gates[bl * 1024 + 256 + jh];
      float gg  = gates[bl * 1024 + 512 + jh];
      float go  = gates[bl * 1024 + 768 + jh];
      c_reg = sigm(gf_) * c_reg + sigm(gi) * tanh_f(gg);
      float hv = sigm(go) * tanh_f(c_reg);
      hh[bl * 256 + jh] = (f16)hv;
      if (isdec)
        out[((size_t)t * 32 + bg) * 256 + jh] = hv;
      else if (isbw)
        out[((size_t)bg * 512 + (511 - t)) * 512 + 256 + jh] = hv;
      else
        out[((size_t)bg * 512 + t) * 512 + jh] = hv;
    }
    __syncthreads();
  }
  if (!isdec && dir == 0 && tid < 512) cf[bg * 256 + jh] = c_reg;
}

// ---------------------------------------------------------------------------
// Attention weights (step-invariant!), context, copy scatter, pctx.
// One block per batch, 512 threads (= L).
// ---------------------------------------------------------------------------
__global__ __launch_bounds__(512) void k_attention(
    const float* __restrict__ enc_out, const float* __restrict__ attn_w,
    const float* __restrict__ pgW, const int* __restrict__ source,
    float* __restrict__ aw_out, float* __restrict__ ctx_out,
    float* __restrict__ pctx, float* __restrict__ copyb) {
  int b = blockIdx.x, tid = threadIdx.x;
  __shared__ float red[512];
  __shared__ float awl[512];
  const float4* row = (const float4*)(enc_out + ((size_t)b * 512 + tid) * 512);
  const float4* wv = (const float4*)attn_w;   // wa_enc = attn_w[0:512]
  float s = 0.f;
  for (int i = 0; i < 128; ++i) {
    float4 r = row[i], w = wv[i];
    s += r.x * w.x + r.y * w.y + r.z * w.z + r.w * w.w;
  }
  red[tid] = s; __syncthreads();
  for (int off = 256; off > 0; off >>= 1) {
    if (tid < off) red[tid] = fmaxf(red[tid], red[tid + off]);
    __syncthreads();
  }
  float m = red[0]; __syncthreads();
  float e = __expf(s - m);
  red[tid] = e; __syncthreads();
  for (int off = 256; off > 0; off >>= 1) {
    if (tid < off) red[tid] += red[tid + off];
    __syncthreads();
  }
  float a = e / red[0];
  __syncthreads();
  awl[tid] = a;
  aw_out[b * 512 + tid] = a;
  atomicAdd(&copyb[(size_t)b * 32000 + source[b * 512 + tid]], a);
  __syncthreads();
  // context: thread = feature index e (512)
  float c = 0.f;
  const float* col = enc_out + (size_t)b * 512 * 512 + tid;
  for (int ll = 0; ll < 512; ++ll) c += awl[ll] * col[(size_t)ll * 512];
  ctx_out[b * 512 + tid] = c;
  red[tid] = c * pgW[256 + tid];
  __syncthreads();
  for (int off = 256; off > 0; off >>= 1) {
    if (tid < off) red[tid] += red[tid + off];
    __syncthreads();
  }
  if (tid == 0) pctx[b] = red[0];
}

// ctxproj[b][j] = dec_b[j] + context[b] . dec_Wih[j][128:640]
__global__ __launch_bounds__(256) void k_ctxproj(
    const float* __restrict__ ctx, const float* __restrict__ dWih,
    const float* __restrict__ db, float* __restrict__ cprj) {
  int b = blockIdx.x, tid = threadIdx.x;
  __shared__ float cs[512];
  cs[tid] = ctx[b * 512 + tid];
  cs[tid + 256] = ctx[b * 512 + 256 + tid];
  __syncthreads();
  const float4* c4 = (const float4*)cs;
  for (int q = 0; q < 4; ++q) {
    int j = q * 256 + tid;
    const float4* wr = (const float4*)(dWih + (size_t)j * 640 + 128);
    float s = db[j];
    for (int i = 0; i < 128; ++i) {
      float4 w = wr[i]; float4 c = c4[i];
      s += w.x * c.x + w.y * c.y + w.z * c.z + w.w * c.w;
    }
    cprj[b * 1024 + j] = s;
  }
}

// p_gen + assemble gen_feat rows (bf16) for the vocab GEMM.
__global__ __launch_bounds__(256) void k_pgen_gf(
    const float* __restrict__ h_all, const float* __restrict__ ctx,
    const float* __restrict__ pgW, const float* __restrict__ pgb,
    const float* __restrict__ pctx, const float* __restrict__ pemb,
    float* __restrict__ pgen, __hip_bfloat16* __restrict__ gf) {
  int r = blockIdx.x, tid = threadIdx.x;   // r = t*32 + b
  int b = r & 31;
  float h = h_all[(size_t)r * 256 + tid];
  gf[(size_t)r * 768 + tid] = __float2bfloat16(h);
  float c0 = ctx[b * 512 + tid], c1 = ctx[b * 512 + 256 + tid];
  gf[(size_t)r * 768 + 256 + tid] = __float2bfloat16(c0);
  gf[(size_t)r * 768 + 512 + tid] = __float2bfloat16(c1);
  __shared__ float red[256];
  red[tid] = h * pgW[tid];
  __syncthreads();
  for (int off = 128; off > 0; off >>= 1) {
    if (tid < off) red[tid] += red[tid + off];
    __syncthreads();
  }
  if (tid == 0) pgen[r] = sigm(red[0] + pctx[b] + pemb[r] + pgb[0]);
}

// ---------------------------------------------------------------------------
// Vocab logits GEMM: (2048 x 768) bf16 @ (32000 x 768)^T bf16 -> fp32 logits
// straight into d_out at [b][t][v]. 128x128 tile, 4 waves, 16x16x32 MFMA.
// ---------------------------------------------------------------------------
__global__ __launch_bounds__(256) void k_logits(
    const __hip_bfloat16* __restrict__ A, const __hip_bfloat16* __restrict__ B,
    const float* __restrict__ vpb, float* __restrict__ out) {
  __shared__ short As[128 * 40];   // pitch 40 halves: bank spread, 16B aligned
  __shared__ short Bs[128 * 40];
  int tid = threadIdx.x;
  int bn = blockIdx.x, bm = blockIdx.y;
  int wave = tid >> 6, lane = tid & 63;
  int q = lane >> 4, m = lane & 15;
  f32x4 acc[2][8];
#pragma unroll
  for (int i = 0; i < 2; ++i)
#pragma unroll
    for (int j = 0; j < 8; ++j)
      acc[i][j] = (f32x4){0.f, 0.f, 0.f, 0.f};
  const short* Ag = (const short*)A + (size_t)(bm * 128) * 768;
  const short* Bg = (const short*)B + (size_t)(bn * 128) * 768;
  int lrow = tid >> 2;
  int lseg = (tid & 3) * 8;
  for (int kc = 0; kc < 768; kc += 32) {
    __syncthreads();
    *(s16x8*)&As[lrow * 40 + lseg] = *(const s16x8*)(Ag + (size_t)lrow * 768 + kc + lseg);
    *(s16x8*)&As[(lrow + 64) * 40 + lseg] = *(const s16x8*)(Ag + (size_t)(lrow + 64) * 768 + kc + lseg);
    *(s16x8*)&Bs[lrow * 40 + lseg] = *(const s16x8*)(Bg + (size_t)lrow * 768 + kc + lseg);
    *(s16x8*)&Bs[(lrow + 64) * 40 + lseg] = *(const s16x8*)(Bg + (size_t)(lrow + 64) * 768 + kc + lseg);
    __syncthreads();
    s16x8 a0 = *(const s16x8*)&As[(wave * 32 + m) * 40 + q * 8];
    s16x8 a1 = *(const s16x8*)&As[(wave * 32 + 16 + m) * 40 + q * 8];
#pragma unroll
    for (int nb = 0; nb < 8; ++nb) {
      s16x8 bf = *(const s16x8*)&Bs[(nb * 16 + m) * 40 + q * 8];
      acc[0][nb] = __builtin_amdgcn_mfma_f32_16x16x32_bf16(a0, bf, acc[0][nb], 0, 0, 0);
      acc[1][nb] = __builtin_amdgcn_mfma_f32_16x16x32_bf16(a1, bf, acc[1][nb], 0, 0, 0);
    }
  }
  // epilogue: D row=(q*4+reg) in M, col=lane&15 in N
#pragma unroll
  for (int mb = 0; mb < 2; ++mb)
#pragma unroll
    for (int nb = 0; nb < 8; ++nb) {
      int v = bn * 128 + nb * 16 + m;
      float vb = vpb[v];
#pragma unroll
      for (int rg = 0; rg < 4; ++rg) {
        int R = bm * 128 + wave * 32 + mb * 16 + q * 4 + rg;   // r = t*32+b
        int bb = R & 31, tt = R >> 5;
        out[((size_t)bb * 64 + tt) * 32000 + v] = acc[mb][nb][rg] + vb;
      }
    }
}

// per-row (b*64+t) inverse sum of exp(logit)
__global__ __launch_bounds__(256) void k_rowsum(const float* __restrict__ out,
                                                float* __restrict__ invs) {
  int row = blockIdx.x, tid = threadIdx.x;
  const float* r = out + (size_t)row * 32000;
  float s = 0.f;
  for (int i = tid; i < 32000; i += 256) s += __expf(r[i]);
  __shared__ float red[256];
  red[tid] = s; __syncthreads();
  for (int off = 128; off > 0; off >>= 1) {
    if (tid < off) red[tid] += red[tid + off];
    __syncthreads();
  }
  if (tid == 0) invs[row] = 1.0f / red[0];
}

// final[b][t][v] = pg*softmax + (1-pg)*copy  (in place over logits)
__global__ __launch_bounds__(256) void k_final(float* __restrict__ out,
                                               const float* __restrict__ invs,
                                               const float* __restrict__ pgen,
                                               const float* __restrict__ copyb) {
  int row = blockIdx.x;              // b*64 + t
  int b = row >> 6, t = row & 63;
  float pg = pgen[t * 32 + b];
  float inv = invs[row];
  float* r = out + (size_t)row * 32000;
  const float* cp = copyb + (size_t)b * 32000;
  for (int i = threadIdx.x; i < 32000; i += 256)
    r[i] = pg * __expf(r[i]) * inv + (1.f - pg) * cp[i];
}

// ---------------------------------------------------------------------------
extern "C" void kernel_launch(void* const* d_in, const int* in_sizes, int n_in,
                              void* d_out, int out_size, void* d_ws, size_t ws_size,
                              hipStream_t stream) {
  (void)in_sizes; (void)n_in; (void)out_size;
  const int*   source = (const int*)d_in[0];
  const int*   target = (const int*)d_in[1];
  const float* embedding = (const float*)d_in[2];
  const float* Wih_f = (const float*)d_in[3];
  const float* Whh_f = (const float*)d_in[4];
  const float* b_f   = (const float*)d_in[5];
  const float* Wih_b = (const float*)d_in[6];
  const float* Whh_b = (const float*)d_in[7];
  const float* b_b   = (const float*)d_in[8];
  const float* dWih  = (const float*)d_in[9];
  const float* dWhh  = (const float*)d_in[10];
  const float* db    = (const float*)d_in[11];
  const float* attn_w = (const float*)d_in[12];
  // d_in[13] attn_b, d_in[14] dp_W, d_in[15] dp_b: dead (softmax shift-invariance)
  const float* vpW = (const float*)d_in[16];
  const float* vpb = (const float*)d_in[17];
  const float* pgW = (const float*)d_in[18];
  const float* pgb = (const float*)d_in[19];

  constexpr size_t OFF_WP   = 0;                          // 3 dirs * 512KB
  constexpr size_t OFF_WIH2 = OFF_WP + 3ull * 32768 * 16;
  constexpr size_t OFF_VP16 = OFF_WIH2 + 3ull * 65536 * 4;
  constexpr size_t OFF_XENC = OFF_VP16 + 24576000ull * 2;
  constexpr size_t OFF_XD   = OFF_XENC + 2ull * 16777216 * 2;
  constexpr size_t OFF_ENCO = OFF_XD + 2097152ull * 2;
  constexpr size_t OFF_CF   = OFF_ENCO + 8388608ull * 4;
  constexpr size_t OFF_AW   = OFF_CF + 32768;
  constexpr size_t OFF_CTX  = OFF_AW + 65536;
  constexpr size_t OFF_CPRJ = OFF_CTX + 65536;
  constexpr size_t OFF_PCTX = OFF_CPRJ + 131072;
  constexpr size_t OFF_PEMB = OFF_PCTX + 128;
  constexpr size_t OFF_PGEN = OFF_PEMB + 8192;
  constexpr size_t OFF_HALL = OFF_PGEN + 8192;
  constexpr size_t OFF_GF   = OFF_HALL + 2097152;
  constexpr size_t OFF_COPY = OFF_GF + 3145728;
  constexpr size_t OFF_INVS = OFF_COPY + 4096000;
  constexpr size_t WS_NEED  = OFF_INVS + 8192;
  if (ws_size < WS_NEED) return;   // workspace too small; fail visibly via absmax

  char* ws = (char*)d_ws;
  uint4* wp             = (uint4*)(ws + OFF_WP);
  unsigned int* wih2f   = (unsigned int*)(ws + OFF_WIH2);
  unsigned int* wih2b   = wih2f + 65536;
  unsigned int* wih2d   = wih2f + 131072;
  __hip_bfloat16* vp16  = (__hip_bfloat16*)(ws + OFF_VP16);
  f16* Xenc             = (f16*)(ws + OFF_XENC);
  f16* Xd               = (f16*)(ws + OFF_XD);
  float* enc_out        = (float*)(ws + OFF_ENCO);
  float* cf             = (float*)(ws + OFF_CF);
  float* aw             = (float*)(ws + OFF_AW);
  float* ctx            = (float*)(ws + OFF_CTX);
  float* cprj           = (float*)(ws + OFF_CPRJ);
  float* pctx           = (float*)(ws + OFF_PCTX);
  float* pemb           = (float*)(ws + OFF_PEMB);
  float* pgen           = (float*)(ws + OFF_PGEN);
  float* h_all          = (float*)(ws + OFF_HALL);
  __hip_bfloat16* gf    = (__hip_bfloat16*)(ws + OFF_GF);
  float* copyb          = (float*)(ws + OFF_COPY);
  float* invs           = (float*)(ws + OFF_INVS);
  float* outp           = (float*)d_out;

  // k_scan v2 uses 156672 B of dynamic LDS (> 64KB default cap).
  constexpr int SCAN_LDS = 156672;
  static bool attr_done = false;
  if (!attr_done) {
    hipFuncSetAttribute((const void*)k_scan,
                        hipFuncAttributeMaxDynamicSharedMemorySize, SCAN_LDS);
    attr_done = true;
  }

  hipMemsetAsync(copyb, 0, 32ull * 32000 * 4, stream);

  k_pack_whh<<<128, 256, 0, stream>>>(Whh_f, wp);
  k_pack_whh<<<128, 256, 0, stream>>>(Whh_b, wp + 32768);
  k_pack_whh<<<128, 256, 0, stream>>>(dWhh,  wp + 65536);
  k_pack_wih<<<256, 256, 0, stream>>>(Wih_f, wih2f, 128);
  k_pack_wih<<<256, 256, 0, stream>>>(Wih_b, wih2b, 128);
  k_pack_wih<<<256, 256, 0, stream>>>(dWih,  wih2d, 640);
  k_pack_vpw<<<96000, 256, 0, stream>>>(vpW, vp16);

  k_encproj<<<512, 256, 0, stream>>>(source, embedding, wih2f, b_f, Xenc, 0);
  k_encproj<<<512, 256, 0, stream>>>(source, embedding, wih2b, b_b,
                                     Xenc + 16777216, 1);
  k_scan<<<32, 1024, SCAN_LDS, stream>>>(wp, Xenc, enc_out, cf, nullptr, 0, 512);
  k_attention<<<32, 512, 0, stream>>>(enc_out, attn_w, pgW, source, aw, ctx,
                                      pctx, copyb);
  k_ctxproj<<<32, 256, 0, stream>>>(ctx, dWih, db, cprj);
  k_decproj<<<64, 256, 0, stream>>>(target, embedding, wih2d, cprj, pgW, Xd,
                                    pemb);
  k_scan<<<16, 1024, SCAN_LDS, stream>>>(wp + 65536, Xd, h_all, cf, enc_out, 2, 64);
  k_pgen_gf<<<2048, 256, 0, stream>>>(h_all, ctx, pgW, pgb, pctx, pemb, pgen,
                                      gf);
  k_logits<<<dim3(250, 16), 256, 0, stream>>>(gf, vp16, vpb, outp);
  k_rowsum<<<2048, 256, 0, stream>>>(outp, invs);
  k_final<<<2048, 256, 0, stream>>>(outp, invs, pgen, copyb);
}

// Round 2
// 2871.087 us; speedup vs baseline: 1.3933x; 1.3933x over previous
//
#include <hip/hip_runtime.h>
#include <hip/hip_bf16.h>

// ---------------------------------------------------------------------------
// PointerGenerator forward, MI355X.
// Key identity: softmax_l(enc_att + const_b) == softmax_l(enc_att)  =>
// attention weights / context / copy-dist are decoder-step-invariant.
// Decoder reduces to an LSTM scan + one big parallel vocab GEMM.
//
// R2 k_scan: gate-local weight-stationary scan.
//  - 256 thr/block, 1 sequence/block. Thread t owns h-dim t's 4 gate columns
//    {t, 256+t, 512+t, 768+t}: activation is thread-local (no gates LDS
//    round-trip, 1 barrier/step via double-buffered h).
//  - Each h-quad LDS broadcast serves 4 columns (32 reads/thread/step).
//  - Whh columns: 23/32 quads in 368 VGPRs (pinned resident via opaque asm —
//    R1 lesson: compiler rematerializes restrict-const loads otherwise),
//    9/32 quads in 147KB LDS with lane-consecutive conflict-free reads.
// ---------------------------------------------------------------------------

#define DEVINL __device__ __forceinline__

typedef _Float16 f16;
typedef _Float16 f16x2 __attribute__((ext_vector_type(2)));
typedef _Float16 f16x8 __attribute__((ext_vector_type(8)));
typedef short    s16x8 __attribute__((ext_vector_type(8)));
typedef float    f32x4 __attribute__((ext_vector_type(4)));
typedef unsigned int u32x4 __attribute__((ext_vector_type(4)));

DEVINL float dot2f(unsigned int a, unsigned int b, float acc) {
#if __has_builtin(__builtin_amdgcn_fdot2)
  return __builtin_amdgcn_fdot2(__builtin_bit_cast(f16x2, a),
                                __builtin_bit_cast(f16x2, b), acc, false);
#else
  f16x2 x = __builtin_bit_cast(f16x2, a);
  f16x2 y = __builtin_bit_cast(f16x2, b);
  return acc + (float)x[0] * (float)y[0] + (float)x[1] * (float)y[1];
#endif
}

DEVINL float sigm(float x) { return 1.0f / (1.0f + __expf(-x)); }
DEVINL float tanh_f(float x) {
  float e = __expf(2.0f * x);
  return (e - 1.0f) / (e + 1.0f);
}
DEVINL unsigned int pack2(float a, float b) {
  f16x2 p; p[0] = (f16)a; p[1] = (f16)b;
  return __builtin_bit_cast(unsigned int, p);
}

// ---------------------------------------------------------------------------
// Weight packing
// ---------------------------------------------------------------------------

// Whh (1024 x 256 fp32) -> Wp[k2b][j] uint4, k2b in [0,32) covers k=8*k2b..+7
__global__ __launch_bounds__(256) void k_pack_whh(const float* __restrict__ W,
                                                  uint4* __restrict__ dst) {
  int id = blockIdx.x * 256 + threadIdx.x;       // 32768
  int k2b = id >> 10, j = id & 1023;
  const float* s = W + (size_t)j * 256 + k2b * 8;
  uint4 u;
  u.x = pack2(s[0], s[1]); u.y = pack2(s[2], s[3]);
  u.z = pack2(s[4], s[5]); u.w = pack2(s[6], s[7]);
  dst[k2b * 1024 + j] = u;
}

// Wih (1024 x ldk fp32, first 128 cols) -> W2[j][k2] uint (half2), k2<64
__global__ __launch_bounds__(256) void k_pack_wih(const float* __restrict__ W,
                                                  unsigned int* __restrict__ dst,
                                                  int ldk) {
  int id = blockIdx.x * 256 + threadIdx.x;       // 65536
  int j = id >> 6, k2 = id & 63;
  dst[j * 64 + k2] = pack2(W[(size_t)j * ldk + 2 * k2],
                           W[(size_t)j * ldk + 2 * k2 + 1]);
}

__global__ __launch_bounds__(256) void k_pack_vpw(const float* __restrict__ W,
                                                  __hip_bfloat16* __restrict__ dst) {
  size_t id = (size_t)blockIdx.x * 256 + threadIdx.x;   // 24,576,000
  dst[id] = __float2bfloat16(W[id]);
}

// ---------------------------------------------------------------------------
// Encoder input projection: X[row][b][j] = emb[b][l] @ Wih.T + bias, f16 out.
// One block per l (256 thr). rev=1 stores to row 511-l (backward direction).
// ---------------------------------------------------------------------------
__global__ __launch_bounds__(256) void k_encproj(
    const int* __restrict__ source, const float* __restrict__ emb,
    const unsigned int* __restrict__ W2, const float* __restrict__ bias,
    f16* __restrict__ X, int rev) {
  int l = blockIdx.x;
  int tid = threadIdx.x;
  __shared__ int toks[32];
  __shared__ unsigned int e2[32 * 66];    // padded rows: bank spread
  if (tid < 32) toks[tid] = source[tid * 512 + l];
  __syncthreads();
  {
    int row = tid >> 3;
    int k2b = (tid & 7) * 8;
    const float* er = emb + (size_t)toks[row] * 128 + k2b * 2;
#pragma unroll
    for (int i = 0; i < 8; ++i)
      e2[row * 66 + k2b + i] = pack2(er[2 * i], er[2 * i + 1]);
  }
  __syncthreads();
  int jg = tid >> 3;        // 0..31 -> j-octet
  int bq = (tid & 7) * 4;   // batch quad base
  int orow = rev ? (511 - l) : l;
  for (int jt = 0; jt < 4; ++jt) {
    int j0 = jt * 256 + jg * 8;
    float acc[8][4];
#pragma unroll
    for (int jj = 0; jj < 8; ++jj) {
      float bv = bias[j0 + jj];
#pragma unroll
      for (int bb = 0; bb < 4; ++bb) acc[jj][bb] = bv;
    }
    for (int kp = 0; kp < 32; ++kp) {
      uint2 w[8], e[4];
#pragma unroll
      for (int jj = 0; jj < 8; ++jj)
        w[jj] = *(const uint2*)(W2 + (size_t)(j0 + jj) * 64 + kp * 2);
#pragma unroll
      for (int bb = 0; bb < 4; ++bb)
        e[bb] = *(const uint2*)(e2 + (bq + bb) * 66 + kp * 2);
#pragma unroll
      for (int jj = 0; jj < 8; ++jj)
#pragma unroll
        for (int bb = 0; bb < 4; ++bb) {
          acc[jj][bb] = dot2f(e[bb].x, w[jj].x, acc[jj][bb]);
          acc[jj][bb] = dot2f(e[bb].y, w[jj].y, acc[jj][bb]);
        }
    }
#pragma unroll
    for (int bb = 0; bb < 4; ++bb) {
      f16x8 v;
#pragma unroll
      for (int jj = 0; jj < 8; ++jj) v[jj] = (f16)acc[jj][bb];
      *(f16x8*)(X + ((size_t)orow * 32 + bq + bb) * 1024 + j0) = v;
    }
  }
}

// ---------------------------------------------------------------------------
// Decoder input projection (emb part only; context part comes via cprj which
// already includes dec_b). Also emits pemb[t][b] = emb_t . pg_W[768:896].
// ---------------------------------------------------------------------------
__global__ __launch_bounds__(256) void k_decproj(
    const int* __restrict__ target, const float* __restrict__ emb,
    const unsigned int* __restrict__ W2, const float* __restrict__ cprj,
    const float* __restrict__ pgW, f16* __restrict__ X,
    float* __restrict__ pemb) {
  int t = blockIdx.x;
  int tid = threadIdx.x;
  __shared__ int toks[32];
  __shared__ unsigned int e2[32 * 66];
  if (tid < 32) toks[tid] = (t == 0) ? 0 : target[tid * 64 + t - 1];
  __syncthreads();
  {
    int row = tid >> 3;
    int k2b = (tid & 7) * 8;
    const float* er = emb + (size_t)toks[row] * 128 + k2b * 2;
#pragma unroll
    for (int i = 0; i < 8; ++i)
      e2[row * 66 + k2b + i] = pack2(er[2 * i], er[2 * i + 1]);
  }
  __syncthreads();
  if (tid < 32) {
    float s = 0.f;
    for (int k2 = 0; k2 < 64; ++k2) {
      f16x2 p = __builtin_bit_cast(f16x2, e2[tid * 66 + k2]);
      s += (float)p[0] * pgW[768 + 2 * k2] + (float)p[1] * pgW[768 + 2 * k2 + 1];
    }
    pemb[t * 32 + tid] = s;
  }
  int jg = tid >> 3;
  int bq = (tid & 7) * 4;
  for (int jt = 0; jt < 4; ++jt) {
    int j0 = jt * 256 + jg * 8;
    float acc[8][4];
#pragma unroll
    for (int jj = 0; jj < 8; ++jj)
#pragma unroll
      for (int bb = 0; bb < 4; ++bb)
        acc[jj][bb] = cprj[(size_t)(bq + bb) * 1024 + j0 + jj];
    for (int kp = 0; kp < 32; ++kp) {
      uint2 w[8], e[4];
#pragma unroll
      for (int jj = 0; jj < 8; ++jj)
        w[jj] = *(const uint2*)(W2 + (size_t)(j0 + jj) * 64 + kp * 2);
#pragma unroll
      for (int bb = 0; bb < 4; ++bb)
        e[bb] = *(const uint2*)(e2 + (bq + bb) * 66 + kp * 2);
#pragma unroll
      for (int jj = 0; jj < 8; ++jj)
#pragma unroll
        for (int bb = 0; bb < 4; ++bb) {
          acc[jj][bb] = dot2f(e[bb].x, w[jj].x, acc[jj][bb]);
          acc[jj][bb] = dot2f(e[bb].y, w[jj].y, acc[jj][bb]);
        }
    }
#pragma unroll
    for (int bb = 0; bb < 4; ++bb) {
      f16x8 v;
#pragma unroll
      for (int jj = 0; jj < 8; ++jj) v[jj] = (f16)acc[jj][bb];
      *(f16x8*)(X + ((size_t)t * 32 + bq + bb) * 1024 + j0) = v;
    }
  }
}

// ---------------------------------------------------------------------------
// LSTM scan v3 — gate-local weight-stationary.
// 256 threads, 1 sequence per block. Thread t: h-dim t, gate columns
// c*256+t (c=0..3 = i,f,g,o). Whh quads [0,23) in VGPRs (pinned), [23,32)
// in LDS. h double-buffered in LDS (one barrier/step), activation local.
// mode 0: encoder, grid 64 (dir = bid>>5). mode 2: decoder, grid 32.
// Dynamic LDS: 9*1024*16 (W) + 2*256*2 (h dbuf) = 148480 B.
// ---------------------------------------------------------------------------
#define PIN23(A)                                                             \
  asm volatile("" : "+v"(A[0]), "+v"(A[1]), "+v"(A[2]), "+v"(A[3]),          \
                    "+v"(A[4]), "+v"(A[5]), "+v"(A[6]), "+v"(A[7]),          \
                    "+v"(A[8]), "+v"(A[9]), "+v"(A[10]), "+v"(A[11]),        \
                    "+v"(A[12]), "+v"(A[13]), "+v"(A[14]), "+v"(A[15]),      \
                    "+v"(A[16]), "+v"(A[17]), "+v"(A[18]), "+v"(A[19]),      \
                    "+v"(A[20]), "+v"(A[21]), "+v"(A[22]))

__global__ __launch_bounds__(256, 1) void k_scan(
    const uint4* __restrict__ Wp0, const f16* __restrict__ X0,
    float* __restrict__ out, float* __restrict__ cf,
    const float* __restrict__ hinit, int mode, int nsteps) {
  extern __shared__ char smem[];
  uint4* WL = (uint4*)smem;                 // [9][1024] quads 23..31
  f16*   hh = (f16*)(smem + 147456);        // [2][256] double buffer
  int bid = blockIdx.x;
  int dir = (mode == 2) ? 0 : (bid >> 5);
  int b   = (mode == 2) ? bid : (bid & 31);
  int isdec = (mode == 2);
  const uint4* Wp = Wp0 + (size_t)dir * 32768;
  const f16* X = X0 + (size_t)dir * 16777216;
  int t_ = threadIdx.x;                     // h-dim / lane role

  // --- resident weights: quads [0,23) for 4 gate columns c*256+t_ ---
  u32x4 w0[23], w1[23], w2[23], w3[23];
#pragma unroll
  for (int q = 0; q < 23; ++q) {
    w0[q] = *(const u32x4*)&Wp[(q << 10) + 0 * 256 + t_];
    w1[q] = *(const u32x4*)&Wp[(q << 10) + 1 * 256 + t_];
    w2[q] = *(const u32x4*)&Wp[(q << 10) + 2 * 256 + t_];
    w3[q] = *(const u32x4*)&Wp[(q << 10) + 3 * 256 + t_];
  }
  // Opaque pin: compiler cannot rematerialize these from memory (R1 lesson).
  PIN23(w0); PIN23(w1); PIN23(w2); PIN23(w3);

  // --- LDS weights: quads [23,32), all 1024 cols, linear copy ---
  for (int i = t_; i < 9 * 1024; i += 256) WL[i] = Wp[23 * 1024 + i];

  // --- init h, c ---
  float c_reg;
  if (isdec) {
    c_reg = cf[b * 256 + t_];
    hh[t_] = (f16)hinit[((size_t)b * 512 + 511) * 512 + t_];
  } else {
    c_reg = 0.f;
    hh[t_] = (f16)0.f;
  }
  __syncthreads();

  const f16* xp = X + (size_t)b * 1024;     // step stride 32*1024
  f16 xc0 = xp[t_], xc1 = xp[256 + t_], xc2 = xp[512 + t_], xc3 = xp[768 + t_];

  for (int t = 0; t < nsteps; ++t) {
    float a0 = (float)xc0, a1 = (float)xc1, a2 = (float)xc2, a3 = (float)xc3;
    if (t + 1 < nsteps) {                   // prefetch next step's x
      const f16* xn = xp + 32768;
      xc0 = xn[t_]; xc1 = xn[256 + t_]; xc2 = xn[512 + t_]; xc3 = xn[768 + t_];
      xp = xn;
    }
    const f16* hb = hh + (t & 1) * 256;
#pragma unroll
    for (int q = 0; q < 23; ++q) {
      u32x4 hq = *(const u32x4*)(hb + q * 8);   // broadcast, serves 4 cols
      a0 = dot2f(hq[0], w0[q][0], a0); a1 = dot2f(hq[0], w1[q][0], a1);
      a2 = dot2f(hq[0], w2[q][0], a2); a3 = dot2f(hq[0], w3[q][0], a3);
      a0 = dot2f(hq[1], w0[q][1], a0); a1 = dot2f(hq[1], w1[q][1], a1);
      a2 = dot2f(hq[1], w2[q][1], a2); a3 = dot2f(hq[1], w3[q][1], a3);
      a0 = dot2f(hq[2], w0[q][2], a0); a1 = dot2f(hq[2], w1[q][2], a1);
      a2 = dot2f(hq[2], w2[q][2], a2); a3 = dot2f(hq[2], w3[q][2], a3);
      a0 = dot2f(hq[3], w0[q][3], a0); a1 = dot2f(hq[3], w1[q][3], a1);
      a2 = dot2f(hq[3], w2[q][3], a2); a3 = dot2f(hq[3], w3[q][3], a3);
    }
#pragma unroll
    for (int q = 23; q < 32; ++q) {
      u32x4 hq = *(const u32x4*)(hb + q * 8);
      u32x4 v0 = *(const u32x4*)&WL[(q - 23) * 1024 + 0 * 256 + t_];
      u32x4 v1 = *(const u32x4*)&WL[(q - 23) * 1024 + 1 * 256 + t_];
      u32x4 v2 = *(const u32x4*)&WL[(q - 23) * 1024 + 2 * 256 + t_];
      u32x4 v3 = *(const u32x4*)&WL[(q - 23) * 1024 + 3 * 256 + t_];
      a0 = dot2f(hq[0], v0[0], a0); a1 = dot2f(hq[0], v1[0], a1);
      a2 = dot2f(hq[0], v2[0], a2); a3 = dot2f(hq[0], v3[0], a3);
      a0 = dot2f(hq[1], v0[1], a0); a1 = dot2f(hq[1], v1[1], a1);
      a2 = dot2f(hq[1], v2[1], a2); a3 = dot2f(hq[1], v3[1], a3);
      a0 = dot2f(hq[2], v0[2], a0); a1 = dot2f(hq[2], v1[2], a1);
      a2 = dot2f(hq[2], v2[2], a2); a3 = dot2f(hq[2], v3[2], a3);
      a0 = dot2f(hq[3], v0[3], a0); a1 = dot2f(hq[3], v1[3], a1);
      a2 = dot2f(hq[3], v2[3], a2); a3 = dot2f(hq[3], v3[3], a3);
    }
    // activation: fully thread-local (a0=i, a1=f, a2=g, a3=o)
    c_reg = sigm(a1) * c_reg + sigm(a0) * tanh_f(a2);
    float hv = sigm(a3) * tanh_f(c_reg);
    hh[((t + 1) & 1) * 256 + t_] = (f16)hv;   // write other buffer: no race
    if (isdec)
      out[((size_t)t * 32 + b) * 256 + t_] = hv;
    else if (dir == 1)
      out[((size_t)b * 512 + (511 - t)) * 512 + 256 + t_] = hv;
    else
      out[((size_t)b * 512 + t) * 512 + t_] = hv;
    __syncthreads();                          // writes visible for next read
  }
  if (!isdec && dir == 0) cf[b * 256 + t_] = c_reg;
}

// ---------------------------------------------------------------------------
// Attention weights (step-invariant!), context, copy scatter, pctx.
// One block per batch, 512 threads (= L).
// ---------------------------------------------------------------------------
__global__ __launch_bounds__(512) void k_attention(
    const float* __restrict__ enc_out, const float* __restrict__ attn_w,
    const float* __restrict__ pgW, const int* __restrict__ source,
    float* __restrict__ aw_out, float* __restrict__ ctx_out,
    float* __restrict__ pctx, float* __restrict__ copyb) {
  int b = blockIdx.x, tid = threadIdx.x;
  __shared__ float red[512];
  __shared__ float awl[512];
  const float4* row = (const float4*)(enc_out + ((size_t)b * 512 + tid) * 512);
  const float4* wv = (const float4*)attn_w;   // wa_enc = attn_w[0:512]
  float s = 0.f;
  for (int i = 0; i < 128; ++i) {
    float4 r = row[i], w = wv[i];
    s += r.x * w.x + r.y * w.y + r.z * w.z + r.w * w.w;
  }
  red[tid] = s; __syncthreads();
  for (int off = 256; off > 0; off >>= 1) {
    if (tid < off) red[tid] = fmaxf(red[tid], red[tid + off]);
    __syncthreads();
  }
  float m = red[0]; __syncthreads();
  float e = __expf(s - m);
  red[tid] = e; __syncthreads();
  for (int off = 256; off > 0; off >>= 1) {
    if (tid < off) red[tid] += red[tid + off];
    __syncthreads();
  }
  float a = e / red[0];
  __syncthreads();
  awl[tid] = a;
  aw_out[b * 512 + tid] = a;
  atomicAdd(&copyb[(size_t)b * 32000 + source[b * 512 + tid]], a);
  __syncthreads();
  // context: thread = feature index e (512)
  float c = 0.f;
  const float* col = enc_out + (size_t)b * 512 * 512 + tid;
  for (int ll = 0; ll < 512; ++ll) c += awl[ll] * col[(size_t)ll * 512];
  ctx_out[b * 512 + tid] = c;
  red[tid] = c * pgW[256 + tid];
  __syncthreads();
  for (int off = 256; off > 0; off >>= 1) {
    if (tid < off) red[tid] += red[tid + off];
    __syncthreads();
  }
  if (tid == 0) pctx[b] = red[0];
}

// ctxproj[b][j] = dec_b[j] + context[b] . dec_Wih[j][128:640]
__global__ __launch_bounds__(256) void k_ctxproj(
    const float* __restrict__ ctx, const float* __restrict__ dWih,
    const float* __restrict__ db, float* __restrict__ cprj) {
  int b = blockIdx.x, tid = threadIdx.x;
  __shared__ float cs[512];
  cs[tid] = ctx[b * 512 + tid];
  cs[tid + 256] = ctx[b * 512 + 256 + tid];
  __syncthreads();
  const float4* c4 = (const float4*)cs;
  for (int q = 0; q < 4; ++q) {
    int j = q * 256 + tid;
    const float4* wr = (const float4*)(dWih + (size_t)j * 640 + 128);
    float s = db[j];
    for (int i = 0; i < 128; ++i) {
      float4 w = wr[i]; float4 c = c4[i];
      s += w.x * c.x + w.y * c.y + w.z * c.z + w.w * c.w;
    }
    cprj[b * 1024 + j] = s;
  }
}

// p_gen + assemble gen_feat rows (bf16) for the vocab GEMM.
__global__ __launch_bounds__(256) void k_pgen_gf(
    const float* __restrict__ h_all, const float* __restrict__ ctx,
    const float* __restrict__ pgW, const float* __restrict__ pgb,
    const float* __restrict__ pctx, const float* __restrict__ pemb,
    float* __restrict__ pgen, __hip_bfloat16* __restrict__ gf) {
  int r = blockIdx.x, tid = threadIdx.x;   // r = t*32 + b
  int b = r & 31;
  float h = h_all[(size_t)r * 256 + tid];
  gf[(size_t)r * 768 + tid] = __float2bfloat16(h);
  float c0 = ctx[b * 512 + tid], c1 = ctx[b * 512 + 256 + tid];
  gf[(size_t)r * 768 + 256 + tid] = __float2bfloat16(c0);
  gf[(size_t)r * 768 + 512 + tid] = __float2bfloat16(c1);
  __shared__ float red[256];
  red[tid] = h * pgW[tid];
  __syncthreads();
  for (int off = 128; off > 0; off >>= 1) {
    if (tid < off) red[tid] += red[tid + off];
    __syncthreads();
  }
  if (tid == 0) pgen[r] = sigm(red[0] + pctx[b] + pemb[r] + pgb[0]);
}

// ---------------------------------------------------------------------------
// Vocab logits GEMM: (2048 x 768) bf16 @ (32000 x 768)^T bf16 -> fp32 logits
// straight into d_out at [b][t][v]. 128x128 tile, 4 waves, 16x16x32 MFMA.
// ---------------------------------------------------------------------------
__global__ __launch_bounds__(256) void k_logits(
    const __hip_bfloat16* __restrict__ A, const __hip_bfloat16* __restrict__ B,
    const float* __restrict__ vpb, float* __restrict__ out) {
  __shared__ short As[128 * 40];   // pitch 40 halves: bank spread, 16B aligned
  __shared__ short Bs[128 * 40];
  int tid = threadIdx.x;
  int bn = blockIdx.x, bm = blockIdx.y;
  int wave = tid >> 6, lane = tid & 63;
  int q = lane >> 4, m = lane & 15;
  f32x4 acc[2][8];
#pragma unroll
  for (int i = 0; i < 2; ++i)
#pragma unroll
    for (int j = 0; j < 8; ++j)
      acc[i][j] = (f32x4){0.f, 0.f, 0.f, 0.f};
  const short* Ag = (const short*)A + (size_t)(bm * 128) * 768;
  const short* Bg = (const short*)B + (size_t)(bn * 128) * 768;
  int lrow = tid >> 2;
  int lseg = (tid & 3) * 8;
  for (int kc = 0; kc < 768; kc += 32) {
    __syncthreads();
    *(s16x8*)&As[lrow * 40 + lseg] = *(const s16x8*)(Ag + (size_t)lrow * 768 + kc + lseg);
    *(s16x8*)&As[(lrow + 64) * 40 + lseg] = *(const s16x8*)(Ag + (size_t)(lrow + 64) * 768 + kc + lseg);
    *(s16x8*)&Bs[lrow * 40 + lseg] = *(const s16x8*)(Bg + (size_t)lrow * 768 + kc + lseg);
    *(s16x8*)&Bs[(lrow + 64) * 40 + lseg] = *(const s16x8*)(Bg + (size_t)(lrow + 64) * 768 + kc + lseg);
    __syncthreads();
    s16x8 a0 = *(const s16x8*)&As[(wave * 32 + m) * 40 + q * 8];
    s16x8 a1 = *(const s16x8*)&As[(wave * 32 + 16 + m) * 40 + q * 8];
#pragma unroll
    for (int nb = 0; nb < 8; ++nb) {
      s16x8 bf = *(const s16x8*)&Bs[(nb * 16 + m) * 40 + q * 8];
      acc[0][nb] = __builtin_amdgcn_mfma_f32_16x16x32_bf16(a0, bf, acc[0][nb], 0, 0, 0);
      acc[1][nb] = __builtin_amdgcn_mfma_f32_16x16x32_bf16(a1, bf, acc[1][nb], 0, 0, 0);
    }
  }
  // epilogue: D row=(q*4+reg) in M, col=lane&15 in N
#pragma unroll
  for (int mb = 0; mb < 2; ++mb)
#pragma unroll
    for (int nb = 0; nb < 8; ++nb) {
      int v = bn * 128 + nb * 16 + m;
      float vb = vpb[v];
#pragma unroll
      for (int rg = 0; rg < 4; ++rg) {
        int R = bm * 128 + wave * 32 + mb * 16 + q * 4 + rg;   // r = t*32+b
        int bb = R & 31, tt = R >> 5;
        out[((size_t)bb * 64 + tt) * 32000 + v] = acc[mb][nb][rg] + vb;
      }
    }
}

// per-row (b*64+t) inverse sum of exp(logit)
__global__ __launch_bounds__(256) void k_rowsum(const float* __restrict__ out,
                                                float* __restrict__ invs) {
  int row = blockIdx.x, tid = threadIdx.x;
  const float* r = out + (size_t)row * 32000;
  float s = 0.f;
  for (int i = tid; i < 32000; i += 256) s += __expf(r[i]);
  __shared__ float red[256];
  red[tid] = s; __syncthreads();
  for (int off = 128; off > 0; off >>= 1) {
    if (tid < off) red[tid] += red[tid + off];
    __syncthreads();
  }
  if (tid == 0) invs[row] = 1.0f / red[0];
}

// final[b][t][v] = pg*softmax + (1-pg)*copy  (in place over logits)
__global__ __launch_bounds__(256) void k_final(float* __restrict__ out,
                                               const float* __restrict__ invs,
                                               const float* __restrict__ pgen,
                                               const float* __restrict__ copyb) {
  int row = blockIdx.x;              // b*64 + t
  int b = row >> 6, t = row & 63;
  float pg = pgen[t * 32 + b];
  float inv = invs[row];
  float* r = out + (size_t)row * 32000;
  const float* cp = copyb + (size_t)b * 32000;
  for (int i = threadIdx.x; i < 32000; i += 256)
    r[i] = pg * __expf(r[i]) * inv + (1.f - pg) * cp[i];
}

// ---------------------------------------------------------------------------
extern "C" void kernel_launch(void* const* d_in, const int* in_sizes, int n_in,
                              void* d_out, int out_size, void* d_ws, size_t ws_size,
                              hipStream_t stream) {
  (void)in_sizes; (void)n_in; (void)out_size;
  const int*   source = (const int*)d_in[0];
  const int*   target = (const int*)d_in[1];
  const float* embedding = (const float*)d_in[2];
  const float* Wih_f = (const float*)d_in[3];
  const float* Whh_f = (const float*)d_in[4];
  const float* b_f   = (const float*)d_in[5];
  const float* Wih_b = (const float*)d_in[6];
  const float* Whh_b = (const float*)d_in[7];
  const float* b_b   = (const float*)d_in[8];
  const float* dWih  = (const float*)d_in[9];
  const float* dWhh  = (const float*)d_in[10];
  const float* db    = (const float*)d_in[11];
  const float* attn_w = (const float*)d_in[12];
  // d_in[13] attn_b, d_in[14] dp_W, d_in[15] dp_b: dead (softmax shift-invariance)
  const float* vpW = (const float*)d_in[16];
  const float* vpb = (const float*)d_in[17];
  const float* pgW = (const float*)d_in[18];
  const float* pgb = (const float*)d_in[19];

  constexpr size_t OFF_WP   = 0;                          // 3 dirs * 512KB
  constexpr size_t OFF_WIH2 = OFF_WP + 3ull * 32768 * 16;
  constexpr size_t OFF_VP16 = OFF_WIH2 + 3ull * 65536 * 4;
  constexpr size_t OFF_XENC = OFF_VP16 + 24576000ull * 2;
  constexpr size_t OFF_XD   = OFF_XENC + 2ull * 16777216 * 2;
  constexpr size_t OFF_ENCO = OFF_XD + 2097152ull * 2;
  constexpr size_t OFF_CF   = OFF_ENCO + 8388608ull * 4;
  constexpr size_t OFF_AW   = OFF_CF + 32768;
  constexpr size_t OFF_CTX  = OFF_AW + 65536;
  constexpr size_t OFF_CPRJ = OFF_CTX + 65536;
  constexpr size_t OFF_PCTX = OFF_CPRJ + 131072;
  constexpr size_t OFF_PEMB = OFF_PCTX + 128;
  constexpr size_t OFF_PGEN = OFF_PEMB + 8192;
  constexpr size_t OFF_HALL = OFF_PGEN + 8192;
  constexpr size_t OFF_GF   = OFF_HALL + 2097152;
  constexpr size_t OFF_COPY = OFF_GF + 3145728;
  constexpr size_t OFF_INVS = OFF_COPY + 4096000;
  constexpr size_t WS_NEED  = OFF_INVS + 8192;
  if (ws_size < WS_NEED) return;   // workspace too small; fail visibly via absmax

  char* ws = (char*)d_ws;
  uint4* wp             = (uint4*)(ws + OFF_WP);
  unsigned int* wih2f   = (unsigned int*)(ws + OFF_WIH2);
  unsigned int* wih2b   = wih2f + 65536;
  unsigned int* wih2d   = wih2f + 131072;
  __hip_bfloat16* vp16  = (__hip_bfloat16*)(ws + OFF_VP16);
  f16* Xenc             = (f16*)(ws + OFF_XENC);
  f16* Xd               = (f16*)(ws + OFF_XD);
  float* enc_out        = (float*)(ws + OFF_ENCO);
  float* cf             = (float*)(ws + OFF_CF);
  float* aw             = (float*)(ws + OFF_AW);
  float* ctx            = (float*)(ws + OFF_CTX);
  float* cprj           = (float*)(ws + OFF_CPRJ);
  float* pctx           = (float*)(ws + OFF_PCTX);
  float* pemb           = (float*)(ws + OFF_PEMB);
  float* pgen           = (float*)(ws + OFF_PGEN);
  float* h_all          = (float*)(ws + OFF_HALL);
  __hip_bfloat16* gf    = (__hip_bfloat16*)(ws + OFF_GF);
  float* copyb          = (float*)(ws + OFF_COPY);
  float* invs           = (float*)(ws + OFF_INVS);
  float* outp           = (float*)d_out;

  // k_scan v3 uses 148480 B of dynamic LDS (> 64KB default cap).
  constexpr int SCAN_LDS = 148480;
  static bool attr_done = false;
  if (!attr_done) {
    hipFuncSetAttribute((const void*)k_scan,
                        hipFuncAttributeMaxDynamicSharedMemorySize, SCAN_LDS);
    attr_done = true;
  }

  hipMemsetAsync(copyb, 0, 32ull * 32000 * 4, stream);

  k_pack_whh<<<128, 256, 0, stream>>>(Whh_f, wp);
  k_pack_whh<<<128, 256, 0, stream>>>(Whh_b, wp + 32768);
  k_pack_whh<<<128, 256, 0, stream>>>(dWhh,  wp + 65536);
  k_pack_wih<<<256, 256, 0, stream>>>(Wih_f, wih2f, 128);
  k_pack_wih<<<256, 256, 0, stream>>>(Wih_b, wih2b, 128);
  k_pack_wih<<<256, 256, 0, stream>>>(dWih,  wih2d, 640);
  k_pack_vpw<<<96000, 256, 0, stream>>>(vpW, vp16);

  k_encproj<<<512, 256, 0, stream>>>(source, embedding, wih2f, b_f, Xenc, 0);
  k_encproj<<<512, 256, 0, stream>>>(source, embedding, wih2b, b_b,
                                     Xenc + 16777216, 1);
  k_scan<<<64, 256, SCAN_LDS, stream>>>(wp, Xenc, enc_out, cf, nullptr, 0, 512);
  k_attention<<<32, 512, 0, stream>>>(enc_out, attn_w, pgW, source, aw, ctx,
                                      pctx, copyb);
  k_ctxproj<<<32, 256, 0, stream>>>(ctx, dWih, db, cprj);
  k_decproj<<<64, 256, 0, stream>>>(target, embedding, wih2d, cprj, pgW, Xd,
                                    pemb);
  k_scan<<<32, 256, SCAN_LDS, stream>>>(wp + 65536, Xd, h_all, cf, enc_out, 2, 64);
  k_pgen_gf<<<2048, 256, 0, stream>>>(h_all, ctx, pgW, pgb, pctx, pemb, pgen,
                                      gf);
  k_logits<<<dim3(250, 16), 256, 0, stream>>>(gf, vp16, vpb, outp);
  k_rowsum<<<2048, 256, 0, stream>>>(outp, invs);
  k_final<<<2048, 256, 0, stream>>>(outp, invs, pgen, copyb);
}

// Round 3
// 2354.585 us; speedup vs baseline: 1.6989x; 1.2194x over previous
//
#include <hip/hip_runtime.h>
#include <hip/hip_bf16.h>

// ---------------------------------------------------------------------------
// PointerGenerator forward, MI355X.
// Key identity: softmax_l(enc_att + const_b) == softmax_l(enc_att)  =>
// attention weights / context / copy-dist are decoder-step-invariant.
// Decoder reduces to an LSTM scan + one big parallel vocab GEMM.
//
// R3 k_scan: K-split weight-stationary scan sized to the DEMONSTRATED
// register budget (R2: allocator sustains ~220 VGPRs, spills beyond).
//  - 512 thr/block, 1 seq/block. Thread t: K-quarter qt=t&3, col-base
//    c0=t>>2; owns cols c0+128i (i=0..7) = gates i,f,g,o for h-dims
//    c0 and c0+128, over a 64-wide K slice.
//  - Weights: 64 quads/thread = 48 in regs (192 VGPR, pinned) + 16 in LDS
//    (128KB). h-slice reads: 8 quads/thread (4x less than full-K), LDS
//    quad-interleaved [qq][qt] so the 4 distinct addrs hit distinct banks.
//  - 4-lane partial reduce via DPP quad-perm butterflies (VALU pipe, not
//    ds_bpermute). Activation redundant in all 4 lanes (bitwise identical),
//    writes predicated to qt==0. One barrier/step (h double-buffered).
// ---------------------------------------------------------------------------

#define DEVINL __device__ __forceinline__

typedef _Float16 f16;
typedef _Float16 f16x2 __attribute__((ext_vector_type(2)));
typedef _Float16 f16x8 __attribute__((ext_vector_type(8)));
typedef short    s16x8 __attribute__((ext_vector_type(8)));
typedef float    f32x4 __attribute__((ext_vector_type(4)));
typedef unsigned int u32x4 __attribute__((ext_vector_type(4)));

DEVINL float dot2f(unsigned int a, unsigned int b, float acc) {
#if __has_builtin(__builtin_amdgcn_fdot2)
  return __builtin_amdgcn_fdot2(__builtin_bit_cast(f16x2, a),
                                __builtin_bit_cast(f16x2, b), acc, false);
#else
  f16x2 x = __builtin_bit_cast(f16x2, a);
  f16x2 y = __builtin_bit_cast(f16x2, b);
  return acc + (float)x[0] * (float)y[0] + (float)x[1] * (float)y[1];
#endif
}

DEVINL float sigm(float x) { return 1.0f / (1.0f + __expf(-x)); }
DEVINL float tanh_f(float x) {
  float e = __expf(2.0f * x);
  return (e - 1.0f) / (e + 1.0f);
}
DEVINL unsigned int pack2(float a, float b) {
  f16x2 p; p[0] = (f16)a; p[1] = (f16)b;
  return __builtin_bit_cast(unsigned int, p);
}

// sum across the 4 lanes of a quad (lanes t, t^1, t^2, t^3) via DPP
// butterflies. All 4 lanes end with the bitwise-identical total.
DEVINL float qsum(float v) {
  int a = __builtin_bit_cast(int, v);
  v += __builtin_bit_cast(float,
        __builtin_amdgcn_mov_dpp(a, 0xB1, 0xF, 0xF, true));   // xor 1
  int b = __builtin_bit_cast(int, v);
  v += __builtin_bit_cast(float,
        __builtin_amdgcn_mov_dpp(b, 0x4E, 0xF, 0xF, true));   // xor 2
  return v;
}

// h-dim d -> swizzled f16 index in the interleaved h buffer.
// Global quad g=d>>3 (qt_o=g>>3, qq_o=g&7) stored at quad slot qq_o*4+qt_o.
DEVINL int hswz(int d) {
  int g = d >> 3;
  return ((g & 7) * 4 + (g >> 3)) * 8 + (d & 7);
}

// ---------------------------------------------------------------------------
// Weight packing
// ---------------------------------------------------------------------------

// Whh (1024 x 256 fp32) -> WQ[s][t] uint4 (s=i*8+qq in [0,64), t in [0,512)):
// thread t (qt=t&3, c0=t>>2), col c=c0+128i, k = qt*64 + qq*8 .. +8.
__global__ __launch_bounds__(256) void k_pack_whh(const float* __restrict__ W,
                                                  uint4* __restrict__ dst) {
  int id = blockIdx.x * 256 + threadIdx.x;       // 32768
  int s = id >> 9, t = id & 511;
  int i = s >> 3, qq = s & 7;
  int c0 = t >> 2, qt = t & 3;
  int c = c0 + (i << 7);
  int kb = qt * 64 + qq * 8;
  const float* src = W + (size_t)c * 256 + kb;
  uint4 u;
  u.x = pack2(src[0], src[1]); u.y = pack2(src[2], src[3]);
  u.z = pack2(src[4], src[5]); u.w = pack2(src[6], src[7]);
  dst[id] = u;
}

// Wih (1024 x ldk fp32, first 128 cols) -> W2[j][k2] uint (half2), k2<64
__global__ __launch_bounds__(256) void k_pack_wih(const float* __restrict__ W,
                                                  unsigned int* __restrict__ dst,
                                                  int ldk) {
  int id = blockIdx.x * 256 + threadIdx.x;       // 65536
  int j = id >> 6, k2 = id & 63;
  dst[j * 64 + k2] = pack2(W[(size_t)j * ldk + 2 * k2],
                           W[(size_t)j * ldk + 2 * k2 + 1]);
}

__global__ __launch_bounds__(256) void k_pack_vpw(const float* __restrict__ W,
                                                  __hip_bfloat16* __restrict__ dst) {
  size_t id = (size_t)blockIdx.x * 256 + threadIdx.x;   // 24,576,000
  dst[id] = __float2bfloat16(W[id]);
}

// ---------------------------------------------------------------------------
// Encoder input projection: X[row][b][j] = emb[b][l] @ Wih.T + bias, f16 out.
// One block per l (256 thr). rev=1 stores to row 511-l (backward direction).
// ---------------------------------------------------------------------------
__global__ __launch_bounds__(256) void k_encproj(
    const int* __restrict__ source, const float* __restrict__ emb,
    const unsigned int* __restrict__ W2, const float* __restrict__ bias,
    f16* __restrict__ X, int rev) {
  int l = blockIdx.x;
  int tid = threadIdx.x;
  __shared__ int toks[32];
  __shared__ unsigned int e2[32 * 66];    // padded rows: bank spread
  if (tid < 32) toks[tid] = source[tid * 512 + l];
  __syncthreads();
  {
    int row = tid >> 3;
    int k2b = (tid & 7) * 8;
    const float* er = emb + (size_t)toks[row] * 128 + k2b * 2;
#pragma unroll
    for (int i = 0; i < 8; ++i)
      e2[row * 66 + k2b + i] = pack2(er[2 * i], er[2 * i + 1]);
  }
  __syncthreads();
  int jg = tid >> 3;        // 0..31 -> j-octet
  int bq = (tid & 7) * 4;   // batch quad base
  int orow = rev ? (511 - l) : l;
  for (int jt = 0; jt < 4; ++jt) {
    int j0 = jt * 256 + jg * 8;
    float acc[8][4];
#pragma unroll
    for (int jj = 0; jj < 8; ++jj) {
      float bv = bias[j0 + jj];
#pragma unroll
      for (int bb = 0; bb < 4; ++bb) acc[jj][bb] = bv;
    }
    for (int kp = 0; kp < 32; ++kp) {
      uint2 w[8], e[4];
#pragma unroll
      for (int jj = 0; jj < 8; ++jj)
        w[jj] = *(const uint2*)(W2 + (size_t)(j0 + jj) * 64 + kp * 2);
#pragma unroll
      for (int bb = 0; bb < 4; ++bb)
        e[bb] = *(const uint2*)(e2 + (bq + bb) * 66 + kp * 2);
#pragma unroll
      for (int jj = 0; jj < 8; ++jj)
#pragma unroll
        for (int bb = 0; bb < 4; ++bb) {
          acc[jj][bb] = dot2f(e[bb].x, w[jj].x, acc[jj][bb]);
          acc[jj][bb] = dot2f(e[bb].y, w[jj].y, acc[jj][bb]);
        }
    }
#pragma unroll
    for (int bb = 0; bb < 4; ++bb) {
      f16x8 v;
#pragma unroll
      for (int jj = 0; jj < 8; ++jj) v[jj] = (f16)acc[jj][bb];
      *(f16x8*)(X + ((size_t)orow * 32 + bq + bb) * 1024 + j0) = v;
    }
  }
}

// ---------------------------------------------------------------------------
// Decoder input projection (emb part only; context part comes via cprj which
// already includes dec_b). Also emits pemb[t][b] = emb_t . pg_W[768:896].
// ---------------------------------------------------------------------------
__global__ __launch_bounds__(256) void k_decproj(
    const int* __restrict__ target, const float* __restrict__ emb,
    const unsigned int* __restrict__ W2, const float* __restrict__ cprj,
    const float* __restrict__ pgW, f16* __restrict__ X,
    float* __restrict__ pemb) {
  int t = blockIdx.x;
  int tid = threadIdx.x;
  __shared__ int toks[32];
  __shared__ unsigned int e2[32 * 66];
  if (tid < 32) toks[tid] = (t == 0) ? 0 : target[tid * 64 + t - 1];
  __syncthreads();
  {
    int row = tid >> 3;
    int k2b = (tid & 7) * 8;
    const float* er = emb + (size_t)toks[row] * 128 + k2b * 2;
#pragma unroll
    for (int i = 0; i < 8; ++i)
      e2[row * 66 + k2b + i] = pack2(er[2 * i], er[2 * i + 1]);
  }
  __syncthreads();
  if (tid < 32) {
    float s = 0.f;
    for (int k2 = 0; k2 < 64; ++k2) {
      f16x2 p = __builtin_bit_cast(f16x2, e2[tid * 66 + k2]);
      s += (float)p[0] * pgW[768 + 2 * k2] + (float)p[1] * pgW[768 + 2 * k2 + 1];
    }
    pemb[t * 32 + tid] = s;
  }
  int jg = tid >> 3;
  int bq = (tid & 7) * 4;
  for (int jt = 0; jt < 4; ++jt) {
    int j0 = jt * 256 + jg * 8;
    float acc[8][4];
#pragma unroll
    for (int jj = 0; jj < 8; ++jj)
#pragma unroll
      for (int bb = 0; bb < 4; ++bb)
        acc[jj][bb] = cprj[(size_t)(bq + bb) * 1024 + j0 + jj];
    for (int kp = 0; kp < 32; ++kp) {
      uint2 w[8], e[4];
#pragma unroll
      for (int jj = 0; jj < 8; ++jj)
        w[jj] = *(const uint2*)(W2 + (size_t)(j0 + jj) * 64 + kp * 2);
#pragma unroll
      for (int bb = 0; bb < 4; ++bb)
        e[bb] = *(const uint2*)(e2 + (bq + bb) * 66 + kp * 2);
#pragma unroll
      for (int jj = 0; jj < 8; ++jj)
#pragma unroll
        for (int bb = 0; bb < 4; ++bb) {
          acc[jj][bb] = dot2f(e[bb].x, w[jj].x, acc[jj][bb]);
          acc[jj][bb] = dot2f(e[bb].y, w[jj].y, acc[jj][bb]);
        }
    }
#pragma unroll
    for (int bb = 0; bb < 4; ++bb) {
      f16x8 v;
#pragma unroll
      for (int jj = 0; jj < 8; ++jj) v[jj] = (f16)acc[jj][bb];
      *(f16x8*)(X + ((size_t)t * 32 + bq + bb) * 1024 + j0) = v;
    }
  }
}

// ---------------------------------------------------------------------------
// LSTM scan v4 — K-split weight-stationary (see header comment).
// mode 0: encoder, grid 64 (dir = bid>>5). mode 2: decoder, grid 32.
// Dynamic LDS: 16*512*16 (W) + 2*256*2 (h dbuf) = 132096 B.
// ---------------------------------------------------------------------------
#define PIN16(A)                                                             \
  asm volatile("" : "+v"((A)[0]), "+v"((A)[1]), "+v"((A)[2]), "+v"((A)[3]),  \
                    "+v"((A)[4]), "+v"((A)[5]), "+v"((A)[6]), "+v"((A)[7]),  \
                    "+v"((A)[8]), "+v"((A)[9]), "+v"((A)[10]), "+v"((A)[11]),\
                    "+v"((A)[12]), "+v"((A)[13]), "+v"((A)[14]), "+v"((A)[15]))

__global__ __launch_bounds__(512, 2) void k_scan(
    const uint4* __restrict__ WQ0, const f16* __restrict__ X0,
    float* __restrict__ out, float* __restrict__ cf,
    const float* __restrict__ hinit, int mode, int nsteps) {
  extern __shared__ char smem[];
  uint4* WL = (uint4*)smem;                  // [16][512] quad rows 48..63
  f16*   hh = (f16*)(smem + 131072);         // [2][256] interleaved layout
  int bid = blockIdx.x;
  int dir = (mode == 2) ? 0 : (bid >> 5);
  int b   = (mode == 2) ? bid : (bid & 31);
  int isdec = (mode == 2);
  const uint4* WQ = WQ0 + (size_t)dir * 32768;
  const f16* X = X0 + (size_t)dir * 16777216;
  int t_ = threadIdx.x;
  int qt = t_ & 3;        // K-quarter: k in [64*qt, 64*qt+64)
  int c0 = t_ >> 2;       // 0..127: h-dims c0, c0+128

  // --- resident weights: quad rows [0,48) (cols i=0..5: gates i,f,g) ---
  u32x4 wr[48];
#pragma unroll
  for (int s = 0; s < 48; ++s) wr[s] = *(const u32x4*)&WQ[s * 512 + t_];
  PIN16(wr); PIN16(wr + 16); PIN16(wr + 32);

  // --- LDS weights: quad rows [48,64) (cols i=6,7: o-gate) ---
  for (int i = t_; i < 16 * 512; i += 512) WL[i] = WQ[48 * 512 + i];

  // --- init h, c (c redundant across the 4 qt lanes, bitwise identical) ---
  float c0r, c1r;
  if (isdec) {
    c0r = cf[b * 256 + c0];
    c1r = cf[b * 256 + 128 + c0];
    if (t_ < 256) hh[hswz(t_)] = (f16)hinit[((size_t)b * 512 + 511) * 512 + t_];
  } else {
    c0r = 0.f; c1r = 0.f;
    if (t_ < 256) hh[t_] = (f16)0.f;        // zeros: layout-independent
  }
  __syncthreads();

  int wi0 = hswz(c0), wi1 = hswz(c0 + 128);  // h write positions (swizzled)
  const f16* xp = X + (size_t)b * 1024;
  float xf[8];
#pragma unroll
  for (int i = 0; i < 8; ++i) xf[i] = (float)xp[c0 + (i << 7)];

  for (int t = 0; t < nsteps; ++t) {
    float xcur[8];
#pragma unroll
    for (int i = 0; i < 8; ++i) xcur[i] = xf[i];
    if (t + 1 < nsteps) {                    // prefetch next step's x
      const f16* xn = xp + 32768;
#pragma unroll
      for (int i = 0; i < 8; ++i) xf[i] = (float)xn[c0 + (i << 7)];
      xp = xn;
    }
    float acc[8];
#pragma unroll
    for (int i = 0; i < 8; ++i) acc[i] = 0.f;
    // h buffer, interleaved: quad slot qq*4+qt holds global quad 8*qt+qq
    const u32x4* hb = (const u32x4*)(hh + (t & 1) * 256);
#pragma unroll
    for (int qq = 0; qq < 8; ++qq) {
      u32x4 hq = hb[qq * 4 + qt];            // 4 distinct addrs -> 4 banksets
#pragma unroll
      for (int i = 0; i < 6; ++i) {
        int s = i * 8 + qq;
        acc[i] = dot2f(hq[0], wr[s][0], acc[i]);
        acc[i] = dot2f(hq[1], wr[s][1], acc[i]);
        acc[i] = dot2f(hq[2], wr[s][2], acc[i]);
        acc[i] = dot2f(hq[3], wr[s][3], acc[i]);
      }
      u32x4 w6 = *(const u32x4*)&WL[qq * 512 + t_];        // s=48+qq
      u32x4 w7 = *(const u32x4*)&WL[(8 + qq) * 512 + t_];  // s=56+qq
      acc[6] = dot2f(hq[0], w6[0], acc[6]);
      acc[6] = dot2f(hq[1], w6[1], acc[6]);
      acc[6] = dot2f(hq[2], w6[2], acc[6]);
      acc[6] = dot2f(hq[3], w6[3], acc[6]);
      acc[7] = dot2f(hq[0], w7[0], acc[7]);
      acc[7] = dot2f(hq[1], w7[1], acc[7]);
      acc[7] = dot2f(hq[2], w7[2], acc[7]);
      acc[7] = dot2f(hq[3], w7[3], acc[7]);
    }
    // reduce K-quarters (DPP, VALU pipe); add x after (once, all lanes same)
#pragma unroll
    for (int i = 0; i < 8; ++i) acc[i] = qsum(acc[i]) + xcur[i];
    // activation: d0=c0 uses acc[0,2,4,6]=i,f,g,o; d1=c0+128 uses acc[1,3,5,7]
    c0r = sigm(acc[2]) * c0r + sigm(acc[0]) * tanh_f(acc[4]);
    float hv0 = sigm(acc[6]) * tanh_f(c0r);
    c1r = sigm(acc[3]) * c1r + sigm(acc[1]) * tanh_f(c1r * 0.f + acc[5]);
    float hv1 = sigm(acc[7]) * tanh_f(c1r);
    f16* hn = hh + ((t + 1) & 1) * 256;
    if (qt == 0) {
      hn[wi0] = (f16)hv0;
      hn[wi1] = (f16)hv1;
      if (isdec) {
        size_t r = ((size_t)t * 32 + b) * 256;
        out[r + c0] = hv0; out[r + 128 + c0] = hv1;
      } else if (dir == 1) {
        size_t r = ((size_t)b * 512 + (511 - t)) * 512 + 256;
        out[r + c0] = hv0; out[r + 128 + c0] = hv1;
      } else {
        size_t r = ((size_t)b * 512 + t) * 512;
        out[r + c0] = hv0; out[r + 128 + c0] = hv1;
      }
    }
    __syncthreads();
  }
  if (!isdec && dir == 0 && qt == 0) {
    cf[b * 256 + c0] = c0r;
    cf[b * 256 + 128 + c0] = c1r;
  }
}

// ---------------------------------------------------------------------------
// Attention weights (step-invariant!), context, copy scatter, pctx.
// One block per batch, 512 threads (= L).
// ---------------------------------------------------------------------------
__global__ __launch_bounds__(512) void k_attention(
    const float* __restrict__ enc_out, const float* __restrict__ attn_w,
    const float* __restrict__ pgW, const int* __restrict__ source,
    float* __restrict__ aw_out, float* __restrict__ ctx_out,
    float* __restrict__ pctx, float* __restrict__ copyb) {
  int b = blockIdx.x, tid = threadIdx.x;
  __shared__ float red[512];
  __shared__ float awl[512];
  const float4* row = (const float4*)(enc_out + ((size_t)b * 512 + tid) * 512);
  const float4* wv = (const float4*)attn_w;   // wa_enc = attn_w[0:512]
  float s = 0.f;
  for (int i = 0; i < 128; ++i) {
    float4 r = row[i], w = wv[i];
    s += r.x * w.x + r.y * w.y + r.z * w.z + r.w * w.w;
  }
  red[tid] = s; __syncthreads();
  for (int off = 256; off > 0; off >>= 1) {
    if (tid < off) red[tid] = fmaxf(red[tid], red[tid + off]);
    __syncthreads();
  }
  float m = red[0]; __syncthreads();
  float e = __expf(s - m);
  red[tid] = e; __syncthreads();
  for (int off = 256; off > 0; off >>= 1) {
    if (tid < off) red[tid] += red[tid + off];
    __syncthreads();
  }
  float a = e / red[0];
  __syncthreads();
  awl[tid] = a;
  aw_out[b * 512 + tid] = a;
  atomicAdd(&copyb[(size_t)b * 32000 + source[b * 512 + tid]], a);
  __syncthreads();
  // context: thread = feature index e (512)
  float c = 0.f;
  const float* col = enc_out + (size_t)b * 512 * 512 + tid;
  for (int ll = 0; ll < 512; ++ll) c += awl[ll] * col[(size_t)ll * 512];
  ctx_out[b * 512 + tid] = c;
  red[tid] = c * pgW[256 + tid];
  __syncthreads();
  for (int off = 256; off > 0; off >>= 1) {
    if (tid < off) red[tid] += red[tid + off];
    __syncthreads();
  }
  if (tid == 0) pctx[b] = red[0];
}

// ctxproj[b][j] = dec_b[j] + context[b] . dec_Wih[j][128:640]
__global__ __launch_bounds__(256) void k_ctxproj(
    const float* __restrict__ ctx, const float* __restrict__ dWih,
    const float* __restrict__ db, float* __restrict__ cprj) {
  int b = blockIdx.x, tid = threadIdx.x;
  __shared__ float cs[512];
  cs[tid] = ctx[b * 512 + tid];
  cs[tid + 256] = ctx[b * 512 + 256 + tid];
  __syncthreads();
  const float4* c4 = (const float4*)cs;
  for (int q = 0; q < 4; ++q) {
    int j = q * 256 + tid;
    const float4* wr = (const float4*)(dWih + (size_t)j * 640 + 128);
    float s = db[j];
    for (int i = 0; i < 128; ++i) {
      float4 w = wr[i]; float4 c = c4[i];
      s += w.x * c.x + w.y * c.y + w.z * c.z + w.w * c.w;
    }
    cprj[b * 1024 + j] = s;
  }
}

// p_gen + assemble gen_feat rows (bf16) for the vocab GEMM.
__global__ __launch_bounds__(256) void k_pgen_gf(
    const float* __restrict__ h_all, const float* __restrict__ ctx,
    const float* __restrict__ pgW, const float* __restrict__ pgb,
    const float* __restrict__ pctx, const float* __restrict__ pemb,
    float* __restrict__ pgen, __hip_bfloat16* __restrict__ gf) {
  int r = blockIdx.x, tid = threadIdx.x;   // r = t*32 + b
  int b = r & 31;
  float h = h_all[(size_t)r * 256 + tid];
  gf[(size_t)r * 768 + tid] = __float2bfloat16(h);
  float c0 = ctx[b * 512 + tid], c1 = ctx[b * 512 + 256 + tid];
  gf[(size_t)r * 768 + 256 + tid] = __float2bfloat16(c0);
  gf[(size_t)r * 768 + 512 + tid] = __float2bfloat16(c1);
  __shared__ float red[256];
  red[tid] = h * pgW[tid];
  __syncthreads();
  for (int off = 128; off > 0; off >>= 1) {
    if (tid < off) red[tid] += red[tid + off];
    __syncthreads();
  }
  if (tid == 0) pgen[r] = sigm(red[0] + pctx[b] + pemb[r] + pgb[0]);
}

// ---------------------------------------------------------------------------
// Vocab logits GEMM: (2048 x 768) bf16 @ (32000 x 768)^T bf16 -> fp32 logits
// straight into d_out at [b][t][v]. 128x128 tile, 4 waves, 16x16x32 MFMA.
// ---------------------------------------------------------------------------
__global__ __launch_bounds__(256) void k_logits(
    const __hip_bfloat16* __restrict__ A, const __hip_bfloat16* __restrict__ B,
    const float* __restrict__ vpb, float* __restrict__ out) {
  __shared__ short As[128 * 40];   // pitch 40 halves: bank spread, 16B aligned
  __shared__ short Bs[128 * 40];
  int tid = threadIdx.x;
  int bn = blockIdx.x, bm = blockIdx.y;
  int wave = tid >> 6, lane = tid & 63;
  int q = lane >> 4, m = lane & 15;
  f32x4 acc[2][8];
#pragma unroll
  for (int i = 0; i < 2; ++i)
#pragma unroll
    for (int j = 0; j < 8; ++j)
      acc[i][j] = (f32x4){0.f, 0.f, 0.f, 0.f};
  const short* Ag = (const short*)A + (size_t)(bm * 128) * 768;
  const short* Bg = (const short*)B + (size_t)(bn * 128) * 768;
  int lrow = tid >> 2;
  int lseg = (tid & 3) * 8;
  for (int kc = 0; kc < 768; kc += 32) {
    __syncthreads();
    *(s16x8*)&As[lrow * 40 + lseg] = *(const s16x8*)(Ag + (size_t)lrow * 768 + kc + lseg);
    *(s16x8*)&As[(lrow + 64) * 40 + lseg] = *(const s16x8*)(Ag + (size_t)(lrow + 64) * 768 + kc + lseg);
    *(s16x8*)&Bs[lrow * 40 + lseg] = *(const s16x8*)(Bg + (size_t)lrow * 768 + kc + lseg);
    *(s16x8*)&Bs[(lrow + 64) * 40 + lseg] = *(const s16x8*)(Bg + (size_t)(lrow + 64) * 768 + kc + lseg);
    __syncthreads();
    s16x8 a0 = *(const s16x8*)&As[(wave * 32 + m) * 40 + q * 8];
    s16x8 a1 = *(const s16x8*)&As[(wave * 32 + 16 + m) * 40 + q * 8];
#pragma unroll
    for (int nb = 0; nb < 8; ++nb) {
      s16x8 bf = *(const s16x8*)&Bs[(nb * 16 + m) * 40 + q * 8];
      acc[0][nb] = __builtin_amdgcn_mfma_f32_16x16x32_bf16(a0, bf, acc[0][nb], 0, 0, 0);
      acc[1][nb] = __builtin_amdgcn_mfma_f32_16x16x32_bf16(a1, bf, acc[1][nb], 0, 0, 0);
    }
  }
  // epilogue: D row=(q*4+reg) in M, col=lane&15 in N
#pragma unroll
  for (int mb = 0; mb < 2; ++mb)
#pragma unroll
    for (int nb = 0; nb < 8; ++nb) {
      int v = bn * 128 + nb * 16 + m;
      float vb = vpb[v];
#pragma unroll
      for (int rg = 0; rg < 4; ++rg) {
        int R = bm * 128 + wave * 32 + mb * 16 + q * 4 + rg;   // r = t*32+b
        int bb = R & 31, tt = R >> 5;
        out[((size_t)bb * 64 + tt) * 32000 + v] = acc[mb][nb][rg] + vb;
      }
    }
}

// per-row (b*64+t) inverse sum of exp(logit)
__global__ __launch_bounds__(256) void k_rowsum(const float* __restrict__ out,
                                                float* __restrict__ invs) {
  int row = blockIdx.x, tid = threadIdx.x;
  const float* r = out + (size_t)row * 32000;
  float s = 0.f;
  for (int i = tid; i < 32000; i += 256) s += __expf(r[i]);
  __shared__ float red[256];
  red[tid] = s; __syncthreads();
  for (int off = 128; off > 0; off >>= 1) {
    if (tid < off) red[tid] += red[tid + off];
    __syncthreads();
  }
  if (tid == 0) invs[row] = 1.0f / red[0];
}

// final[b][t][v] = pg*softmax + (1-pg)*copy  (in place over logits)
__global__ __launch_bounds__(256) void k_final(float* __restrict__ out,
                                               const float* __restrict__ invs,
                                               const float* __restrict__ pgen,
                                               const float* __restrict__ copyb) {
  int row = blockIdx.x;              // b*64 + t
  int b = row >> 6, t = row & 63;
  float pg = pgen[t * 32 + b];
  float inv = invs[row];
  float* r = out + (size_t)row * 32000;
  const float* cp = copyb + (size_t)b * 32000;
  for (int i = threadIdx.x; i < 32000; i += 256)
    r[i] = pg * __expf(r[i]) * inv + (1.f - pg) * cp[i];
}

// ---------------------------------------------------------------------------
extern "C" void kernel_launch(void* const* d_in, const int* in_sizes, int n_in,
                              void* d_out, int out_size, void* d_ws, size_t ws_size,
                              hipStream_t stream) {
  (void)in_sizes; (void)n_in; (void)out_size;
  const int*   source = (const int*)d_in[0];
  const int*   target = (const int*)d_in[1];
  const float* embedding = (const float*)d_in[2];
  const float* Wih_f = (const float*)d_in[3];
  const float* Whh_f = (const float*)d_in[4];
  const float* b_f   = (const float*)d_in[5];
  const float* Wih_b = (const float*)d_in[6];
  const float* Whh_b = (const float*)d_in[7];
  const float* b_b   = (const float*)d_in[8];
  const float* dWih  = (const float*)d_in[9];
  const float* dWhh  = (const float*)d_in[10];
  const float* db    = (const float*)d_in[11];
  const float* attn_w = (const float*)d_in[12];
  // d_in[13] attn_b, d_in[14] dp_W, d_in[15] dp_b: dead (softmax shift-invariance)
  const float* vpW = (const float*)d_in[16];
  const float* vpb = (const float*)d_in[17];
  const float* pgW = (const float*)d_in[18];
  const float* pgb = (const float*)d_in[19];

  constexpr size_t OFF_WP   = 0;                          // 3 dirs * 512KB
  constexpr size_t OFF_WIH2 = OFF_WP + 3ull * 32768 * 16;
  constexpr size_t OFF_VP16 = OFF_WIH2 + 3ull * 65536 * 4;
  constexpr size_t OFF_XENC = OFF_VP16 + 24576000ull * 2;
  constexpr size_t OFF_XD   = OFF_XENC + 2ull * 16777216 * 2;
  constexpr size_t OFF_ENCO = OFF_XD + 2097152ull * 2;
  constexpr size_t OFF_CF   = OFF_ENCO + 8388608ull * 4;
  constexpr size_t OFF_AW   = OFF_CF + 32768;
  constexpr size_t OFF_CTX  = OFF_AW + 65536;
  constexpr size_t OFF_CPRJ = OFF_CTX + 65536;
  constexpr size_t OFF_PCTX = OFF_CPRJ + 131072;
  constexpr size_t OFF_PEMB = OFF_PCTX + 128;
  constexpr size_t OFF_PGEN = OFF_PEMB + 8192;
  constexpr size_t OFF_HALL = OFF_PGEN + 8192;
  constexpr size_t OFF_GF   = OFF_HALL + 2097152;
  constexpr size_t OFF_COPY = OFF_GF + 3145728;
  constexpr size_t OFF_INVS = OFF_COPY + 4096000;
  constexpr size_t WS_NEED  = OFF_INVS + 8192;
  if (ws_size < WS_NEED) return;   // workspace too small; fail visibly via absmax

  char* ws = (char*)d_ws;
  uint4* wp             = (uint4*)(ws + OFF_WP);
  unsigned int* wih2f   = (unsigned int*)(ws + OFF_WIH2);
  unsigned int* wih2b   = wih2f + 65536;
  unsigned int* wih2d   = wih2f + 131072;
  __hip_bfloat16* vp16  = (__hip_bfloat16*)(ws + OFF_VP16);
  f16* Xenc             = (f16*)(ws + OFF_XENC);
  f16* Xd               = (f16*)(ws + OFF_XD);
  float* enc_out        = (float*)(ws + OFF_ENCO);
  float* cf             = (float*)(ws + OFF_CF);
  float* aw             = (float*)(ws + OFF_AW);
  float* ctx            = (float*)(ws + OFF_CTX);
  float* cprj           = (float*)(ws + OFF_CPRJ);
  float* pctx           = (float*)(ws + OFF_PCTX);
  float* pemb           = (float*)(ws + OFF_PEMB);
  float* pgen           = (float*)(ws + OFF_PGEN);
  float* h_all          = (float*)(ws + OFF_HALL);
  __hip_bfloat16* gf    = (__hip_bfloat16*)(ws + OFF_GF);
  float* copyb          = (float*)(ws + OFF_COPY);
  float* invs           = (float*)(ws + OFF_INVS);
  float* outp           = (float*)d_out;

  // k_scan v4 uses 132096 B of dynamic LDS (> 64KB default cap).
  constexpr int SCAN_LDS = 132096;
  static bool attr_done = false;
  if (!attr_done) {
    hipFuncSetAttribute((const void*)k_scan,
                        hipFuncAttributeMaxDynamicSharedMemorySize, SCAN_LDS);
    attr_done = true;
  }

  hipMemsetAsync(copyb, 0, 32ull * 32000 * 4, stream);

  k_pack_whh<<<128, 256, 0, stream>>>(Whh_f, wp);
  k_pack_whh<<<128, 256, 0, stream>>>(Whh_b, wp + 32768);
  k_pack_whh<<<128, 256, 0, stream>>>(dWhh,  wp + 65536);
  k_pack_wih<<<256, 256, 0, stream>>>(Wih_f, wih2f, 128);
  k_pack_wih<<<256, 256, 0, stream>>>(Wih_b, wih2b, 128);
  k_pack_wih<<<256, 256, 0, stream>>>(dWih,  wih2d, 640);
  k_pack_vpw<<<96000, 256, 0, stream>>>(vpW, vp16);

  k_encproj<<<512, 256, 0, stream>>>(source, embedding, wih2f, b_f, Xenc, 0);
  k_encproj<<<512, 256, 0, stream>>>(source, embedding, wih2b, b_b,
                                     Xenc + 16777216, 1);
  k_scan<<<64, 512, SCAN_LDS, stream>>>(wp, Xenc, enc_out, cf, nullptr, 0, 512);
  k_attention<<<32, 512, 0, stream>>>(enc_out, attn_w, pgW, source, aw, ctx,
                                      pctx, copyb);
  k_ctxproj<<<32, 256, 0, stream>>>(ctx, dWih, db, cprj);
  k_decproj<<<64, 256, 0, stream>>>(target, embedding, wih2d, cprj, pgW, Xd,
                                    pemb);
  k_scan<<<32, 512, SCAN_LDS, stream>>>(wp + 65536, Xd, h_all, cf, enc_out, 2, 64);
  k_pgen_gf<<<2048, 256, 0, stream>>>(h_all, ctx, pgW, pgb, pctx, pemb, pgen,
                                      gf);
  k_logits<<<dim3(250, 16), 256, 0, stream>>>(gf, vp16, vpb, outp);
  k_rowsum<<<2048, 256, 0, stream>>>(outp, invs);
  k_final<<<2048, 256, 0, stream>>>(outp, invs, pgen, copyb);
}

// Round 4
// 2350.948 us; speedup vs baseline: 1.7016x; 1.0015x over previous
//
#include <hip/hip_runtime.h>
#include <hip/hip_bf16.h>

// ---------------------------------------------------------------------------
// PointerGenerator forward, MI355X.
// Key identity: softmax_l(enc_att + const_b) == softmax_l(enc_att)  =>
// attention weights / context / copy-dist are decoder-step-invariant.
// Decoder reduces to an LSTM scan + one big parallel vocab GEMM.
//
// R4 k_scan: K-split weight-stationary scan (R3 structure) with the register
// cap fixed. R3 lesson: __launch_bounds__(512,2) capped the allocator at 128
// VGPRs -> ~24/48 pinned weight quads spilled to scratch, reloaded every
// step (~3.9K cyc/step of scratch traffic). (512,1) raises the cap to 256;
// ask is 192 pinned + ~48 working = ~240. Grid is 64 blocks on 256 CUs so
// >1 block/CU buys nothing anyway.
//  - 512 thr/block, 1 seq/block. Thread t: K-quarter qt=t&3, col-base
//    c0=t>>2; owns cols c0+128i (i=0..7) = gates i,f,g,o for h-dims
//    c0 and c0+128, over a 64-wide K slice.
//  - Weights: 64 quads/thread = 48 in regs (192 VGPR, pinned) + 16 in LDS
//    (128KB). h-slice reads: 8 quads/thread, LDS quad-interleaved [qq][qt]
//    so the 4 distinct addrs hit distinct banks.
//  - 4-lane partial reduce via DPP quad-perm butterflies (VALU pipe).
//    Activation redundant in all 4 lanes, writes predicated to qt==0.
//    One barrier/step (h double-buffered).
// ---------------------------------------------------------------------------

#define DEVINL __device__ __forceinline__

typedef _Float16 f16;
typedef _Float16 f16x2 __attribute__((ext_vector_type(2)));
typedef _Float16 f16x8 __attribute__((ext_vector_type(8)));
typedef short    s16x8 __attribute__((ext_vector_type(8)));
typedef float    f32x4 __attribute__((ext_vector_type(4)));
typedef unsigned int u32x4 __attribute__((ext_vector_type(4)));

DEVINL float dot2f(unsigned int a, unsigned int b, float acc) {
#if __has_builtin(__builtin_amdgcn_fdot2)
  return __builtin_amdgcn_fdot2(__builtin_bit_cast(f16x2, a),
                                __builtin_bit_cast(f16x2, b), acc, false);
#else
  f16x2 x = __builtin_bit_cast(f16x2, a);
  f16x2 y = __builtin_bit_cast(f16x2, b);
  return acc + (float)x[0] * (float)y[0] + (float)x[1] * (float)y[1];
#endif
}

DEVINL float sigm(float x) { return 1.0f / (1.0f + __expf(-x)); }
DEVINL float tanh_f(float x) {
  float e = __expf(2.0f * x);
  return (e - 1.0f) / (e + 1.0f);
}
DEVINL unsigned int pack2(float a, float b) {
  f16x2 p; p[0] = (f16)a; p[1] = (f16)b;
  return __builtin_bit_cast(unsigned int, p);
}

// sum across the 4 lanes of a quad (lanes t, t^1, t^2, t^3) via DPP
// butterflies. All 4 lanes end with the bitwise-identical total.
DEVINL float qsum(float v) {
  int a = __builtin_bit_cast(int, v);
  v += __builtin_bit_cast(float,
        __builtin_amdgcn_mov_dpp(a, 0xB1, 0xF, 0xF, true));   // xor 1
  int b = __builtin_bit_cast(int, v);
  v += __builtin_bit_cast(float,
        __builtin_amdgcn_mov_dpp(b, 0x4E, 0xF, 0xF, true));   // xor 2
  return v;
}

// h-dim d -> swizzled f16 index in the interleaved h buffer.
// Global quad g=d>>3 (qt_o=g>>3, qq_o=g&7) stored at quad slot qq_o*4+qt_o.
DEVINL int hswz(int d) {
  int g = d >> 3;
  return ((g & 7) * 4 + (g >> 3)) * 8 + (d & 7);
}

// ---------------------------------------------------------------------------
// Weight packing
// ---------------------------------------------------------------------------

// Whh (1024 x 256 fp32) -> WQ[s][t] uint4 (s=i*8+qq in [0,64), t in [0,512)):
// thread t (qt=t&3, c0=t>>2), col c=c0+128i, k = qt*64 + qq*8 .. +8.
__global__ __launch_bounds__(256) void k_pack_whh(const float* __restrict__ W,
                                                  uint4* __restrict__ dst) {
  int id = blockIdx.x * 256 + threadIdx.x;       // 32768
  int s = id >> 9, t = id & 511;
  int i = s >> 3, qq = s & 7;
  int c0 = t >> 2, qt = t & 3;
  int c = c0 + (i << 7);
  int kb = qt * 64 + qq * 8;
  const float* src = W + (size_t)c * 256 + kb;
  uint4 u;
  u.x = pack2(src[0], src[1]); u.y = pack2(src[2], src[3]);
  u.z = pack2(src[4], src[5]); u.w = pack2(src[6], src[7]);
  dst[id] = u;
}

// Wih (1024 x ldk fp32, first 128 cols) -> W2[j][k2] uint (half2), k2<64
__global__ __launch_bounds__(256) void k_pack_wih(const float* __restrict__ W,
                                                  unsigned int* __restrict__ dst,
                                                  int ldk) {
  int id = blockIdx.x * 256 + threadIdx.x;       // 65536
  int j = id >> 6, k2 = id & 63;
  dst[j * 64 + k2] = pack2(W[(size_t)j * ldk + 2 * k2],
                           W[(size_t)j * ldk + 2 * k2 + 1]);
}

__global__ __launch_bounds__(256) void k_pack_vpw(const float* __restrict__ W,
                                                  __hip_bfloat16* __restrict__ dst) {
  size_t id = (size_t)blockIdx.x * 256 + threadIdx.x;   // 24,576,000
  dst[id] = __float2bfloat16(W[id]);
}

// ---------------------------------------------------------------------------
// Encoder input projection: X[row][b][j] = emb[b][l] @ Wih.T + bias, f16 out.
// One block per l (256 thr). rev=1 stores to row 511-l (backward direction).
// ---------------------------------------------------------------------------
__global__ __launch_bounds__(256) void k_encproj(
    const int* __restrict__ source, const float* __restrict__ emb,
    const unsigned int* __restrict__ W2, const float* __restrict__ bias,
    f16* __restrict__ X, int rev) {
  int l = blockIdx.x;
  int tid = threadIdx.x;
  __shared__ int toks[32];
  __shared__ unsigned int e2[32 * 66];    // padded rows: bank spread
  if (tid < 32) toks[tid] = source[tid * 512 + l];
  __syncthreads();
  {
    int row = tid >> 3;
    int k2b = (tid & 7) * 8;
    const float* er = emb + (size_t)toks[row] * 128 + k2b * 2;
#pragma unroll
    for (int i = 0; i < 8; ++i)
      e2[row * 66 + k2b + i] = pack2(er[2 * i], er[2 * i + 1]);
  }
  __syncthreads();
  int jg = tid >> 3;        // 0..31 -> j-octet
  int bq = (tid & 7) * 4;   // batch quad base
  int orow = rev ? (511 - l) : l;
  for (int jt = 0; jt < 4; ++jt) {
    int j0 = jt * 256 + jg * 8;
    float acc[8][4];
#pragma unroll
    for (int jj = 0; jj < 8; ++jj) {
      float bv = bias[j0 + jj];
#pragma unroll
      for (int bb = 0; bb < 4; ++bb) acc[jj][bb] = bv;
    }
    for (int kp = 0; kp < 32; ++kp) {
      uint2 w[8], e[4];
#pragma unroll
      for (int jj = 0; jj < 8; ++jj)
        w[jj] = *(const uint2*)(W2 + (size_t)(j0 + jj) * 64 + kp * 2);
#pragma unroll
      for (int bb = 0; bb < 4; ++bb)
        e[bb] = *(const uint2*)(e2 + (bq + bb) * 66 + kp * 2);
#pragma unroll
      for (int jj = 0; jj < 8; ++jj)
#pragma unroll
        for (int bb = 0; bb < 4; ++bb) {
          acc[jj][bb] = dot2f(e[bb].x, w[jj].x, acc[jj][bb]);
          acc[jj][bb] = dot2f(e[bb].y, w[jj].y, acc[jj][bb]);
        }
    }
#pragma unroll
    for (int bb = 0; bb < 4; ++bb) {
      f16x8 v;
#pragma unroll
      for (int jj = 0; jj < 8; ++jj) v[jj] = (f16)acc[jj][bb];
      *(f16x8*)(X + ((size_t)orow * 32 + bq + bb) * 1024 + j0) = v;
    }
  }
}

// ---------------------------------------------------------------------------
// Decoder input projection (emb part only; context part comes via cprj which
// already includes dec_b). Also emits pemb[t][b] = emb_t . pg_W[768:896].
// ---------------------------------------------------------------------------
__global__ __launch_bounds__(256) void k_decproj(
    const int* __restrict__ target, const float* __restrict__ emb,
    const unsigned int* __restrict__ W2, const float* __restrict__ cprj,
    const float* __restrict__ pgW, f16* __restrict__ X,
    float* __restrict__ pemb) {
  int t = blockIdx.x;
  int tid = threadIdx.x;
  __shared__ int toks[32];
  __shared__ unsigned int e2[32 * 66];
  if (tid < 32) toks[tid] = (t == 0) ? 0 : target[tid * 64 + t - 1];
  __syncthreads();
  {
    int row = tid >> 3;
    int k2b = (tid & 7) * 8;
    const float* er = emb + (size_t)toks[row] * 128 + k2b * 2;
#pragma unroll
    for (int i = 0; i < 8; ++i)
      e2[row * 66 + k2b + i] = pack2(er[2 * i], er[2 * i + 1]);
  }
  __syncthreads();
  if (tid < 32) {
    float s = 0.f;
    for (int k2 = 0; k2 < 64; ++k2) {
      f16x2 p = __builtin_bit_cast(f16x2, e2[tid * 66 + k2]);
      s += (float)p[0] * pgW[768 + 2 * k2] + (float)p[1] * pgW[768 + 2 * k2 + 1];
    }
    pemb[t * 32 + tid] = s;
  }
  int jg = tid >> 3;
  int bq = (tid & 7) * 4;
  for (int jt = 0; jt < 4; ++jt) {
    int j0 = jt * 256 + jg * 8;
    float acc[8][4];
#pragma unroll
    for (int jj = 0; jj < 8; ++jj)
#pragma unroll
      for (int bb = 0; bb < 4; ++bb)
        acc[jj][bb] = cprj[(size_t)(bq + bb) * 1024 + j0 + jj];
    for (int kp = 0; kp < 32; ++kp) {
      uint2 w[8], e[4];
#pragma unroll
      for (int jj = 0; jj < 8; ++jj)
        w[jj] = *(const uint2*)(W2 + (size_t)(j0 + jj) * 64 + kp * 2);
#pragma unroll
      for (int bb = 0; bb < 4; ++bb)
        e[bb] = *(const uint2*)(e2 + (bq + bb) * 66 + kp * 2);
#pragma unroll
      for (int jj = 0; jj < 8; ++jj)
#pragma unroll
        for (int bb = 0; bb < 4; ++bb) {
          acc[jj][bb] = dot2f(e[bb].x, w[jj].x, acc[jj][bb]);
          acc[jj][bb] = dot2f(e[bb].y, w[jj].y, acc[jj][bb]);
        }
    }
#pragma unroll
    for (int bb = 0; bb < 4; ++bb) {
      f16x8 v;
#pragma unroll
      for (int jj = 0; jj < 8; ++jj) v[jj] = (f16)acc[jj][bb];
      *(f16x8*)(X + ((size_t)t * 32 + bq + bb) * 1024 + j0) = v;
    }
  }
}

// ---------------------------------------------------------------------------
// LSTM scan v5 — K-split weight-stationary (see header comment).
// mode 0: encoder, grid 64 (dir = bid>>5). mode 2: decoder, grid 32.
// Dynamic LDS: 16*512*16 (W) + 2*256*2 (h dbuf) = 132096 B.
// ---------------------------------------------------------------------------
#define PIN16(A)                                                             \
  asm volatile("" : "+v"((A)[0]), "+v"((A)[1]), "+v"((A)[2]), "+v"((A)[3]),  \
                    "+v"((A)[4]), "+v"((A)[5]), "+v"((A)[6]), "+v"((A)[7]),  \
                    "+v"((A)[8]), "+v"((A)[9]), "+v"((A)[10]), "+v"((A)[11]),\
                    "+v"((A)[12]), "+v"((A)[13]), "+v"((A)[14]), "+v"((A)[15]))

__global__ __launch_bounds__(512, 1) void k_scan(
    const uint4* __restrict__ WQ0, const f16* __restrict__ X0,
    float* __restrict__ out, float* __restrict__ cf,
    const float* __restrict__ hinit, int mode, int nsteps) {
  extern __shared__ char smem[];
  uint4* WL = (uint4*)smem;                  // [16][512] quad rows 48..63
  f16*   hh = (f16*)(smem + 131072);         // [2][256] interleaved layout
  int bid = blockIdx.x;
  int dir = (mode == 2) ? 0 : (bid >> 5);
  int b   = (mode == 2) ? bid : (bid & 31);
  int isdec = (mode == 2);
  const uint4* WQ = WQ0 + (size_t)dir * 32768;
  const f16* X = X0 + (size_t)dir * 16777216;
  int t_ = threadIdx.x;
  int qt = t_ & 3;        // K-quarter: k in [64*qt, 64*qt+64)
  int c0 = t_ >> 2;       // 0..127: h-dims c0, c0+128

  // --- resident weights: quad rows [0,48) (cols i=0..5: gates i,f,g) ---
  u32x4 wr[48];
#pragma unroll
  for (int s = 0; s < 48; ++s) wr[s] = *(const u32x4*)&WQ[s * 512 + t_];
  PIN16(wr); PIN16(wr + 16); PIN16(wr + 32);

  // --- LDS weights: quad rows [48,64) (cols i=6,7: o-gate) ---
  for (int i = t_; i < 16 * 512; i += 512) WL[i] = WQ[48 * 512 + i];

  // --- init h, c (c redundant across the 4 qt lanes, bitwise identical) ---
  float c0r, c1r;
  if (isdec) {
    c0r = cf[b * 256 + c0];
    c1r = cf[b * 256 + 128 + c0];
    if (t_ < 256) hh[hswz(t_)] = (f16)hinit[((size_t)b * 512 + 511) * 512 + t_];
  } else {
    c0r = 0.f; c1r = 0.f;
    if (t_ < 256) hh[t_] = (f16)0.f;        // zeros: layout-independent
  }
  __syncthreads();

  int wi0 = hswz(c0), wi1 = hswz(c0 + 128);  // h write positions (swizzled)
  const f16* xp = X + (size_t)b * 1024;
  float xf[8];
#pragma unroll
  for (int i = 0; i < 8; ++i) xf[i] = (float)xp[c0 + (i << 7)];

  for (int t = 0; t < nsteps; ++t) {
    float xcur[8];
#pragma unroll
    for (int i = 0; i < 8; ++i) xcur[i] = xf[i];
    if (t + 1 < nsteps) {                    // prefetch next step's x
      const f16* xn = xp + 32768;
#pragma unroll
      for (int i = 0; i < 8; ++i) xf[i] = (float)xn[c0 + (i << 7)];
      xp = xn;
    }
    float acc[8];
#pragma unroll
    for (int i = 0; i < 8; ++i) acc[i] = 0.f;
    // h buffer, interleaved: quad slot qq*4+qt holds global quad 8*qt+qq
    const u32x4* hb = (const u32x4*)(hh + (t & 1) * 256);
#pragma unroll
    for (int qq = 0; qq < 8; ++qq) {
      u32x4 hq = hb[qq * 4 + qt];            // 4 distinct addrs -> 4 banksets
#pragma unroll
      for (int i = 0; i < 6; ++i) {
        int s = i * 8 + qq;
        acc[i] = dot2f(hq[0], wr[s][0], acc[i]);
        acc[i] = dot2f(hq[1], wr[s][1], acc[i]);
        acc[i] = dot2f(hq[2], wr[s][2], acc[i]);
        acc[i] = dot2f(hq[3], wr[s][3], acc[i]);
      }
      u32x4 w6 = *(const u32x4*)&WL[qq * 512 + t_];        // s=48+qq
      u32x4 w7 = *(const u32x4*)&WL[(8 + qq) * 512 + t_];  // s=56+qq
      acc[6] = dot2f(hq[0], w6[0], acc[6]);
      acc[6] = dot2f(hq[1], w6[1], acc[6]);
      acc[6] = dot2f(hq[2], w6[2], acc[6]);
      acc[6] = dot2f(hq[3], w6[3], acc[6]);
      acc[7] = dot2f(hq[0], w7[0], acc[7]);
      acc[7] = dot2f(hq[1], w7[1], acc[7]);
      acc[7] = dot2f(hq[2], w7[2], acc[7]);
      acc[7] = dot2f(hq[3], w7[3], acc[7]);
    }
    // reduce K-quarters (DPP, VALU pipe); add x after (once, all lanes same)
#pragma unroll
    for (int i = 0; i < 8; ++i) acc[i] = qsum(acc[i]) + xcur[i];
    // activation: d0=c0 uses acc[0,2,4,6]=i,f,g,o; d1=c0+128 uses acc[1,3,5,7]
    c0r = sigm(acc[2]) * c0r + sigm(acc[0]) * tanh_f(acc[4]);
    float hv0 = sigm(acc[6]) * tanh_f(c0r);
    c1r = sigm(acc[3]) * c1r + sigm(acc[1]) * tanh_f(acc[5]);
    float hv1 = sigm(acc[7]) * tanh_f(c1r);
    f16* hn = hh + ((t + 1) & 1) * 256;
    if (qt == 0) {
      hn[wi0] = (f16)hv0;
      hn[wi1] = (f16)hv1;
      if (isdec) {
        size_t r = ((size_t)t * 32 + b) * 256;
        out[r + c0] = hv0; out[r + 128 + c0] = hv1;
      } else if (dir == 1) {
        size_t r = ((size_t)b * 512 + (511 - t)) * 512 + 256;
        out[r + c0] = hv0; out[r + 128 + c0] = hv1;
      } else {
        size_t r = ((size_t)b * 512 + t) * 512;
        out[r + c0] = hv0; out[r + 128 + c0] = hv1;
      }
    }
    __syncthreads();
  }
  if (!isdec && dir == 0 && qt == 0) {
    cf[b * 256 + c0] = c0r;
    cf[b * 256 + 128 + c0] = c1r;
  }
}

// ---------------------------------------------------------------------------
// Attention weights (step-invariant!), context, copy scatter, pctx.
// One block per batch, 512 threads (= L).
// ---------------------------------------------------------------------------
__global__ __launch_bounds__(512) void k_attention(
    const float* __restrict__ enc_out, const float* __restrict__ attn_w,
    const float* __restrict__ pgW, const int* __restrict__ source,
    float* __restrict__ aw_out, float* __restrict__ ctx_out,
    float* __restrict__ pctx, float* __restrict__ copyb) {
  int b = blockIdx.x, tid = threadIdx.x;
  __shared__ float red[512];
  __shared__ float awl[512];
  const float4* row = (const float4*)(enc_out + ((size_t)b * 512 + tid) * 512);
  const float4* wv = (const float4*)attn_w;   // wa_enc = attn_w[0:512]
  float s = 0.f;
  for (int i = 0; i < 128; ++i) {
    float4 r = row[i], w = wv[i];
    s += r.x * w.x + r.y * w.y + r.z * w.z + r.w * w.w;
  }
  red[tid] = s; __syncthreads();
  for (int off = 256; off > 0; off >>= 1) {
    if (tid < off) red[tid] = fmaxf(red[tid], red[tid + off]);
    __syncthreads();
  }
  float m = red[0]; __syncthreads();
  float e = __expf(s - m);
  red[tid] = e; __syncthreads();
  for (int off = 256; off > 0; off >>= 1) {
    if (tid < off) red[tid] += red[tid + off];
    __syncthreads();
  }
  float a = e / red[0];
  __syncthreads();
  awl[tid] = a;
  aw_out[b * 512 + tid] = a;
  atomicAdd(&copyb[(size_t)b * 32000 + source[b * 512 + tid]], a);
  __syncthreads();
  // context: thread = feature index e (512)
  float c = 0.f;
  const float* col = enc_out + (size_t)b * 512 * 512 + tid;
  for (int ll = 0; ll < 512; ++ll) c += awl[ll] * col[(size_t)ll * 512];
  ctx_out[b * 512 + tid] = c;
  red[tid] = c * pgW[256 + tid];
  __syncthreads();
  for (int off = 256; off > 0; off >>= 1) {
    if (tid < off) red[tid] += red[tid + off];
    __syncthreads();
  }
  if (tid == 0) pctx[b] = red[0];
}

// ctxproj[b][j] = dec_b[j] + context[b] . dec_Wih[j][128:640]
__global__ __launch_bounds__(256) void k_ctxproj(
    const float* __restrict__ ctx, const float* __restrict__ dWih,
    const float* __restrict__ db, float* __restrict__ cprj) {
  int b = blockIdx.x, tid = threadIdx.x;
  __shared__ float cs[512];
  cs[tid] = ctx[b * 512 + tid];
  cs[tid + 256] = ctx[b * 512 + 256 + tid];
  __syncthreads();
  const float4* c4 = (const float4*)cs;
  for (int q = 0; q < 4; ++q) {
    int j = q * 256 + tid;
    const float4* wr = (const float4*)(dWih + (size_t)j * 640 + 128);
    float s = db[j];
    for (int i = 0; i < 128; ++i) {
      float4 w = wr[i]; float4 c = c4[i];
      s += w.x * c.x + w.y * c.y + w.z * c.z + w.w * c.w;
    }
    cprj[b * 1024 + j] = s;
  }
}

// p_gen + assemble gen_feat rows (bf16) for the vocab GEMM.
__global__ __launch_bounds__(256) void k_pgen_gf(
    const float* __restrict__ h_all, const float* __restrict__ ctx,
    const float* __restrict__ pgW, const float* __restrict__ pgb,
    const float* __restrict__ pctx, const float* __restrict__ pemb,
    float* __restrict__ pgen, __hip_bfloat16* __restrict__ gf) {
  int r = blockIdx.x, tid = threadIdx.x;   // r = t*32 + b
  int b = r & 31;
  float h = h_all[(size_t)r * 256 + tid];
  gf[(size_t)r * 768 + tid] = __float2bfloat16(h);
  float c0 = ctx[b * 512 + tid], c1 = ctx[b * 512 + 256 + tid];
  gf[(size_t)r * 768 + 256 + tid] = __float2bfloat16(c0);
  gf[(size_t)r * 768 + 512 + tid] = __float2bfloat16(c1);
  __shared__ float red[256];
  red[tid] = h * pgW[tid];
  __syncthreads();
  for (int off = 128; off > 0; off >>= 1) {
    if (tid < off) red[tid] += red[tid + off];
    __syncthreads();
  }
  if (tid == 0) pgen[r] = sigm(red[0] + pctx[b] + pemb[r] + pgb[0]);
}

// ---------------------------------------------------------------------------
// Vocab logits GEMM: (2048 x 768) bf16 @ (32000 x 768)^T bf16 -> fp32 logits
// straight into d_out at [b][t][v]. 128x128 tile, 4 waves, 16x16x32 MFMA.
// ---------------------------------------------------------------------------
__global__ __launch_bounds__(256) void k_logits(
    const __hip_bfloat16* __restrict__ A, const __hip_bfloat16* __restrict__ B,
    const float* __restrict__ vpb, float* __restrict__ out) {
  __shared__ short As[128 * 40];   // pitch 40 halves: bank spread, 16B aligned
  __shared__ short Bs[128 * 40];
  int tid = threadIdx.x;
  int bn = blockIdx.x, bm = blockIdx.y;
  int wave = tid >> 6, lane = tid & 63;
  int q = lane >> 4, m = lane & 15;
  f32x4 acc[2][8];
#pragma unroll
  for (int i = 0; i < 2; ++i)
#pragma unroll
    for (int j = 0; j < 8; ++j)
      acc[i][j] = (f32x4){0.f, 0.f, 0.f, 0.f};
  const short* Ag = (const short*)A + (size_t)(bm * 128) * 768;
  const short* Bg = (const short*)B + (size_t)(bn * 128) * 768;
  int lrow = tid >> 2;
  int lseg = (tid & 3) * 8;
  for (int kc = 0; kc < 768; kc += 32) {
    __syncthreads();
    *(s16x8*)&As[lrow * 40 + lseg] = *(const s16x8*)(Ag + (size_t)lrow * 768 + kc + lseg);
    *(s16x8*)&As[(lrow + 64) * 40 + lseg] = *(const s16x8*)(Ag + (size_t)(lrow + 64) * 768 + kc + lseg);
    *(s16x8*)&Bs[lrow * 40 + lseg] = *(const s16x8*)(Bg + (size_t)lrow * 768 + kc + lseg);
    *(s16x8*)&Bs[(lrow + 64) * 40 + lseg] = *(const s16x8*)(Bg + (size_t)(lrow + 64) * 768 + kc + lseg);
    __syncthreads();
    s16x8 a0 = *(const s16x8*)&As[(wave * 32 + m) * 40 + q * 8];
    s16x8 a1 = *(const s16x8*)&As[(wave * 32 + 16 + m) * 40 + q * 8];
#pragma unroll
    for (int nb = 0; nb < 8; ++nb) {
      s16x8 bf = *(const s16x8*)&Bs[(nb * 16 + m) * 40 + q * 8];
      acc[0][nb] = __builtin_amdgcn_mfma_f32_16x16x32_bf16(a0, bf, acc[0][nb], 0, 0, 0);
      acc[1][nb] = __builtin_amdgcn_mfma_f32_16x16x32_bf16(a1, bf, acc[1][nb], 0, 0, 0);
    }
  }
  // epilogue: D row=(q*4+reg) in M, col=lane&15 in N
#pragma unroll
  for (int mb = 0; mb < 2; ++mb)
#pragma unroll
    for (int nb = 0; nb < 8; ++nb) {
      int v = bn * 128 + nb * 16 + m;
      float vb = vpb[v];
#pragma unroll
      for (int rg = 0; rg < 4; ++rg) {
        int R = bm * 128 + wave * 32 + mb * 16 + q * 4 + rg;   // r = t*32+b
        int bb = R & 31, tt = R >> 5;
        out[((size_t)bb * 64 + tt) * 32000 + v] = acc[mb][nb][rg] + vb;
      }
    }
}

// per-row (b*64+t) inverse sum of exp(logit)
__global__ __launch_bounds__(256) void k_rowsum(const float* __restrict__ out,
                                                float* __restrict__ invs) {
  int row = blockIdx.x, tid = threadIdx.x;
  const float* r = out + (size_t)row * 32000;
  float s = 0.f;
  for (int i = tid; i < 32000; i += 256) s += __expf(r[i]);
  __shared__ float red[256];
  red[tid] = s; __syncthreads();
  for (int off = 128; off > 0; off >>= 1) {
    if (tid < off) red[tid] += red[tid + off];
    __syncthreads();
  }
  if (tid == 0) invs[row] = 1.0f / red[0];
}

// final[b][t][v] = pg*softmax + (1-pg)*copy  (in place over logits)
__global__ __launch_bounds__(256) void k_final(float* __restrict__ out,
                                               const float* __restrict__ invs,
                                               const float* __restrict__ pgen,
                                               const float* __restrict__ copyb) {
  int row = blockIdx.x;              // b*64 + t
  int b = row >> 6, t = row & 63;
  float pg = pgen[t * 32 + b];
  float inv = invs[row];
  float* r = out + (size_t)row * 32000;
  const float* cp = copyb + (size_t)b * 32000;
  for (int i = threadIdx.x; i < 32000; i += 256)
    r[i] = pg * __expf(r[i]) * inv + (1.f - pg) * cp[i];
}

// ---------------------------------------------------------------------------
extern "C" void kernel_launch(void* const* d_in, const int* in_sizes, int n_in,
                              void* d_out, int out_size, void* d_ws, size_t ws_size,
                              hipStream_t stream) {
  (void)in_sizes; (void)n_in; (void)out_size;
  const int*   source = (const int*)d_in[0];
  const int*   target = (const int*)d_in[1];
  const float* embedding = (const float*)d_in[2];
  const float* Wih_f = (const float*)d_in[3];
  const float* Whh_f = (const float*)d_in[4];
  const float* b_f   = (const float*)d_in[5];
  const float* Wih_b = (const float*)d_in[6];
  const float* Whh_b = (const float*)d_in[7];
  const float* b_b   = (const float*)d_in[8];
  const float* dWih  = (const float*)d_in[9];
  const float* dWhh  = (const float*)d_in[10];
  const float* db    = (const float*)d_in[11];
  const float* attn_w = (const float*)d_in[12];
  // d_in[13] attn_b, d_in[14] dp_W, d_in[15] dp_b: dead (softmax shift-invariance)
  const float* vpW = (const float*)d_in[16];
  const float* vpb = (const float*)d_in[17];
  const float* pgW = (const float*)d_in[18];
  const float* pgb = (const float*)d_in[19];

  constexpr size_t OFF_WP   = 0;                          // 3 dirs * 512KB
  constexpr size_t OFF_WIH2 = OFF_WP + 3ull * 32768 * 16;
  constexpr size_t OFF_VP16 = OFF_WIH2 + 3ull * 65536 * 4;
  constexpr size_t OFF_XENC = OFF_VP16 + 24576000ull * 2;
  constexpr size_t OFF_XD   = OFF_XENC + 2ull * 16777216 * 2;
  constexpr size_t OFF_ENCO = OFF_XD + 2097152ull * 2;
  constexpr size_t OFF_CF   = OFF_ENCO + 8388608ull * 4;
  constexpr size_t OFF_AW   = OFF_CF + 32768;
  constexpr size_t OFF_CTX  = OFF_AW + 65536;
  constexpr size_t OFF_CPRJ = OFF_CTX + 65536;
  constexpr size_t OFF_PCTX = OFF_CPRJ + 131072;
  constexpr size_t OFF_PEMB = OFF_PCTX + 128;
  constexpr size_t OFF_PGEN = OFF_PEMB + 8192;
  constexpr size_t OFF_HALL = OFF_PGEN + 8192;
  constexpr size_t OFF_GF   = OFF_HALL + 2097152;
  constexpr size_t OFF_COPY = OFF_GF + 3145728;
  constexpr size_t OFF_INVS = OFF_COPY + 4096000;
  constexpr size_t WS_NEED  = OFF_INVS + 8192;
  if (ws_size < WS_NEED) return;   // workspace too small; fail visibly via absmax

  char* ws = (char*)d_ws;
  uint4* wp             = (uint4*)(ws + OFF_WP);
  unsigned int* wih2f   = (unsigned int*)(ws + OFF_WIH2);
  unsigned int* wih2b   = wih2f + 65536;
  unsigned int* wih2d   = wih2f + 131072;
  __hip_bfloat16* vp16  = (__hip_bfloat16*)(ws + OFF_VP16);
  f16* Xenc             = (f16*)(ws + OFF_XENC);
  f16* Xd               = (f16*)(ws + OFF_XD);
  float* enc_out        = (float*)(ws + OFF_ENCO);
  float* cf             = (float*)(ws + OFF_CF);
  float* aw             = (float*)(ws + OFF_AW);
  float* ctx            = (float*)(ws + OFF_CTX);
  float* cprj           = (float*)(ws + OFF_CPRJ);
  float* pctx           = (float*)(ws + OFF_PCTX);
  float* pemb           = (float*)(ws + OFF_PEMB);
  float* pgen           = (float*)(ws + OFF_PGEN);
  float* h_all          = (float*)(ws + OFF_HALL);
  __hip_bfloat16* gf    = (__hip_bfloat16*)(ws + OFF_GF);
  float* copyb          = (float*)(ws + OFF_COPY);
  float* invs           = (float*)(ws + OFF_INVS);
  float* outp           = (float*)d_out;

  // k_scan v5 uses 132096 B of dynamic LDS (> 64KB default cap).
  constexpr int SCAN_LDS = 132096;
  static bool attr_done = false;
  if (!attr_done) {
    hipFuncSetAttribute((const void*)k_scan,
                        hipFuncAttributeMaxDynamicSharedMemorySize, SCAN_LDS);
    attr_done = true;
  }

  hipMemsetAsync(copyb, 0, 32ull * 32000 * 4, stream);

  k_pack_whh<<<128, 256, 0, stream>>>(Whh_f, wp);
  k_pack_whh<<<128, 256, 0, stream>>>(Whh_b, wp + 32768);
  k_pack_whh<<<128, 256, 0, stream>>>(dWhh,  wp + 65536);
  k_pack_wih<<<256, 256, 0, stream>>>(Wih_f, wih2f, 128);
  k_pack_wih<<<256, 256, 0, stream>>>(Wih_b, wih2b, 128);
  k_pack_wih<<<256, 256, 0, stream>>>(dWih,  wih2d, 640);
  k_pack_vpw<<<96000, 256, 0, stream>>>(vpW, vp16);

  k_encproj<<<512, 256, 0, stream>>>(source, embedding, wih2f, b_f, Xenc, 0);
  k_encproj<<<512, 256, 0, stream>>>(source, embedding, wih2b, b_b,
                                     Xenc + 16777216, 1);
  k_scan<<<64, 512, SCAN_LDS, stream>>>(wp, Xenc, enc_out, cf, nullptr, 0, 512);
  k_attention<<<32, 512, 0, stream>>>(enc_out, attn_w, pgW, source, aw, ctx,
                                      pctx, copyb);
  k_ctxproj<<<32, 256, 0, stream>>>(ctx, dWih, db, cprj);
  k_decproj<<<64, 256, 0, stream>>>(target, embedding, wih2d, cprj, pgW, Xd,
                                    pemb);
  k_scan<<<32, 512, SCAN_LDS, stream>>>(wp + 65536, Xd, h_all, cf, enc_out, 2, 64);
  k_pgen_gf<<<2048, 256, 0, stream>>>(h_all, ctx, pgW, pgb, pctx, pemb, pgen,
                                      gf);
  k_logits<<<dim3(250, 16), 256, 0, stream>>>(gf, vp16, vpb, outp);
  k_rowsum<<<2048, 256, 0, stream>>>(outp, invs);
  k_final<<<2048, 256, 0, stream>>>(outp, invs, pgen, copyb);
}